// Round 11
// baseline (463.635 us; speedup 1.0000x reference)
//
#include <hip/hip_runtime.h>

#define D 64

typedef __attribute__((ext_vector_type(8))) short short8;
typedef __attribute__((ext_vector_type(4))) float f32x4;

__device__ __forceinline__ ushort f2b(float f) {
    union { float f; unsigned u; } x; x.f = f;
    unsigned r = x.u + 0x7FFFu + ((x.u >> 16) & 1u);   // RNE to bf16
    return (ushort)(r >> 16);
}
__device__ __forceinline__ float b2f(ushort u) {
    union { float f; unsigned u; } x; x.u = ((unsigned)u) << 16;
    return x.f;
}
__device__ __forceinline__ short8 pack8(float4 a, float4 b) {
    short8 r;
    r[0] = (short)f2b(a.x); r[1] = (short)f2b(a.y); r[2] = (short)f2b(a.z); r[3] = (short)f2b(a.w);
    r[4] = (short)f2b(b.x); r[5] = (short)f2b(b.y); r[6] = (short)f2b(b.z); r[7] = (short)f2b(b.w);
    return r;
}

// ---------------------------------------------------------------------------
// fused_front: blocks [0, NPB)           -> node_proj + nfp
//              blocks [NPB, NPB+HB)      -> dst histogram
//              block  NPB+HB             -> Wcomb/bias2 setup
// ---------------------------------------------------------------------------
__global__ __launch_bounds__(256) void fused_front_kernel(
    const float* __restrict__ nf, const float* __restrict__ Wn,
    const float* __restrict__ bias, const float* __restrict__ Wd,   // full W_dense
    float* __restrict__ out, ushort* __restrict__ nfp_b, int N,
    const int* __restrict__ dst, int* __restrict__ deg_i, int E,
    const float* __restrict__ W_edge, const float* __restrict__ b_dense,
    const float* __restrict__ bias_edge, ushort* __restrict__ Wcomb_b,
    float* __restrict__ bias2, int NPB, int HB)
{
    __shared__ float Ws[D * D];
    __shared__ float Wb[D * D];
    __shared__ float As[16 * D];
    __shared__ float Vs[16 * D];
    const int tid = threadIdx.x;
    const int bid = blockIdx.x;

    if (bid < NPB) {
        constexpr int ROWS = 16;
        const long row0 = (long)bid * ROWS;
        const float* Wd_bot = Wd + D * D;
        #pragma unroll
        for (int i = tid; i < D * D / 4; i += 256) {
            ((float4*)Ws)[i] = ((const float4*)Wn)[i];
            float4 v = ((const float4*)Wd_bot)[i];
            ((float4*)Wb)[i] = make_float4(0.5f * v.x, 0.5f * v.y, 0.5f * v.z, 0.5f * v.w);
        }
        {
            int i = tid;  // ROWS*D/4 == 256
            long r = row0 + (i * 4) / D;
            ((float4*)As)[i] = (r < N) ? ((const float4*)nf)[row0 * D / 4 + i]
                                       : make_float4(0.f, 0.f, 0.f, 0.f);
        }
        __syncthreads();

        const int c = tid & 63;
        const float b = bias[c];
        for (int rr = tid >> 6; rr < ROWS; rr += 4) {
            float acc = 0.f;
            #pragma unroll
            for (int k = 0; k < D; ++k)
                acc = fmaf(As[rr * D + k], Ws[k * D + c], acc);
            float v = fmaxf(acc + b, 0.f);
            Vs[rr * D + c] = v;
            long r = row0 + rr;
            if (r < N) __builtin_nontemporal_store(v, &out[r * D + c]);
        }
        __syncthreads();
        for (int rr = tid >> 6; rr < ROWS; rr += 4) {
            float acc = 0.f;
            #pragma unroll
            for (int k = 0; k < D; ++k)
                acc = fmaf(Vs[rr * D + k], Wb[k * D + c], acc);
            long r = row0 + rr;
            if (r < N) nfp_b[r * D + c] = f2b(acc);
        }
    } else if (bid < NPB + HB) {
        int i = (bid - NPB) * 256 + tid;
        if (i < E) atomicAdd(deg_i + dst[i], 1);
    } else {
        // setup: Wcomb_b[n*64+k] = bf16((W_edge @ Wd_top)[k][n]); bias2
        for (int idx = tid; idx < D * D; idx += 256) {
            int k = idx >> 6, n = idx & 63;
            float s = 0.f;
            #pragma unroll 8
            for (int j = 0; j < D; ++j)
                s = fmaf(W_edge[k * D + j], Wd[j * D + n], s);
            Wcomb_b[n * D + k] = f2b(s);
        }
        if (tid < D) bias2[tid] = b_dense[tid] + bias_edge[tid];
    }
}

// ---------------------------------------------------------------------------
// Counting sort of edges by dst: (hist in fused_front) -> scan x3 -> scatter
// ---------------------------------------------------------------------------
__global__ __launch_bounds__(256) void scanA_kernel(
    const int* __restrict__ deg_i, int* __restrict__ pos,
    int* __restrict__ bsum, int N)
{
    __shared__ int s[256];
    const int tid = threadIdx.x;
    const int i = blockIdx.x * 256 + tid;
    int v = (i < N) ? deg_i[i] : 0;
    s[tid] = v;
    __syncthreads();
    #pragma unroll
    for (int off = 1; off < 256; off <<= 1) {
        int t = (tid >= off) ? s[tid - off] : 0;
        __syncthreads();
        s[tid] += t;
        __syncthreads();
    }
    if (i < N) pos[i] = s[tid] - v;          // block-local exclusive
    if (tid == 255) bsum[blockIdx.x] = s[255];
}

__global__ __launch_bounds__(256) void scanB_kernel(int* __restrict__ bsum, int NB)
{
    __shared__ int s[256];
    const int tid = threadIdx.x;
    int v = (tid < NB) ? bsum[tid] : 0;
    s[tid] = v;
    __syncthreads();
    #pragma unroll
    for (int off = 1; off < 256; off <<= 1) {
        int t = (tid >= off) ? s[tid - off] : 0;
        __syncthreads();
        s[tid] += t;
        __syncthreads();
    }
    if (tid < NB) bsum[tid] = s[tid] - v;    // exclusive
}

__global__ __launch_bounds__(256) void scanC_kernel(
    const int* __restrict__ pos, int* __restrict__ cursor,
    const int* __restrict__ bsum, int N)
{
    int i = blockIdx.x * 256 + threadIdx.x;
    if (i < N) cursor[i] = pos[i] + bsum[blockIdx.x];
}

__global__ __launch_bounds__(256) void scatter_kernel(
    const int* __restrict__ dst, int* __restrict__ cursor,
    int2* __restrict__ sorted_ed, int E)
{
    int i = blockIdx.x * 256 + threadIdx.x;
    if (i < E) {
        int dv = dst[i];
        int slot = atomicAdd(cursor + dv, 1);
        sorted_ed[slot] = make_int2(i, dv);
    }
}

// ---------------------------------------------------------------------------
// efp_stream: efp = bf16(ef @ Wcomb), fully sequential both sides.
// 64 rows/block, 4 waves, K=64 MFMA; packed dword stores.
// ---------------------------------------------------------------------------
__global__ __launch_bounds__(256) void efp_stream_kernel(
    const float* __restrict__ ef, const ushort* __restrict__ Wt,
    ushort* __restrict__ efp, int E)
{
    const int tid = threadIdx.x;
    const long row0 = (long)blockIdx.x * 64;
    const int w = tid >> 6, lane = tid & 63;
    const int lr = lane & 15, g = lane >> 4;
    const int arow = 16 * w + lr;
    long era = row0 + arow; if (era >= E) era = E - 1;

    const float4* ap = (const float4*)(ef + era * D);
    float4 v0 = ap[2 * g], v1 = ap[2 * g + 1];
    float4 v2 = ap[8 + 2 * g], v3 = ap[8 + 2 * g + 1];
    short8 a0 = pack8(v0, v1), a1 = pack8(v2, v3);

    f32x4 acc[4];
    #pragma unroll
    for (int t = 0; t < 4; ++t) {
        f32x4 z = {0.f, 0.f, 0.f, 0.f};
        short8 b0 = *(const short8*)&Wt[(16 * t + lr) * D + 8 * g];
        short8 b1 = *(const short8*)&Wt[(16 * t + lr) * D + 32 + 8 * g];
        z = __builtin_amdgcn_mfma_f32_16x16x32_bf16(a0, b0, z, 0, 0, 0);
        z = __builtin_amdgcn_mfma_f32_16x16x32_bf16(a1, b1, z, 0, 0, 0);
        acc[t] = z;
    }

    const bool odd = lane & 1;
    const int rb = 16 * w + 4 * g + (odd ? 2 : 0);
    long e0 = row0 + rb, e1 = row0 + rb + 1;
    #pragma unroll
    for (int t = 0; t < 4; ++t) {
        float p0 = __shfl_xor(acc[t][0], 1, 64);
        float p1 = __shfl_xor(acc[t][1], 1, 64);
        float p2 = __shfl_xor(acc[t][2], 1, 64);
        float p3 = __shfl_xor(acc[t][3], 1, 64);
        float lo0, hi0, lo1, hi1;
        if (odd) { lo0 = p2; hi0 = acc[t][2]; lo1 = p3; hi1 = acc[t][3]; }
        else     { lo0 = acc[t][0]; hi0 = p0; lo1 = acc[t][1]; hi1 = p1; }
        int cbase = 16 * t + (lr & ~1);
        unsigned dw0 = ((unsigned)f2b(hi0) << 16) | (unsigned)f2b(lo0);
        unsigned dw1 = ((unsigned)f2b(hi1) << 16) | (unsigned)f2b(lo1);
        if (e0 < E) *(unsigned*)(efp + e0 * D + cbase) = dw0;
        if (e1 < E) *(unsigned*)(efp + e1 * D + cbase) = dw1;
    }
}

// ---------------------------------------------------------------------------
// seg_gather: THE one permutation pass. Persistent 1024 blocks, 2-chunk
// software pipeline: while walking chunk c (LDS + atomics), chunk c+stride's
// sorted_ed and efp-row gathers are already in flight.
// ---------------------------------------------------------------------------
#define SG_CH 128
__global__ __launch_bounds__(256) void seg_gather_kernel(
    const ushort* __restrict__ efp, const int2* __restrict__ sorted_ed,
    float* __restrict__ nb_sum, int E, int nch, int stride)
{
    __shared__ unsigned Slds[SG_CH * 36];   // 36-dword row stride: 16B-aligned rows
    __shared__ int dsts[SG_CH];
    const int tid = threadIdx.x;
    const int r_ = tid >> 3, c8 = tid & 7;

    int c = blockIdx.x;
    if (c >= nch) return;

    int2 id[4]; short8 row[4];
    #pragma unroll
    for (int p = 0; p < 4; ++p) {
        long s = (long)c * SG_CH + r_ + 32 * p;
        if (s >= E) s = E - 1;
        id[p] = sorted_ed[s];
    }
    #pragma unroll
    for (int p = 0; p < 4; ++p)
        row[p] = *(const short8*)(efp + (long)id[p].x * D + c8 * 8);

    while (true) {
        const int cn = c + stride;
        const bool more = (cn < nch);
        int2 idn[4];
        if (more) {
            #pragma unroll
            for (int p = 0; p < 4; ++p) {
                long s = (long)cn * SG_CH + r_ + 32 * p;
                if (s >= E) s = E - 1;
                idn[p] = sorted_ed[s];
            }
        }
        // stage current chunk into LDS
        #pragma unroll
        for (int p = 0; p < 4; ++p) {
            int r = r_ + 32 * p;
            *(uint4*)&Slds[r * 36 + c8 * 4] = *(uint4*)&row[p];
            if (c8 == 0) {
                long s = (long)c * SG_CH + r;
                dsts[r] = (s < E) ? id[p].y : -1;
            }
        }
        __syncthreads();
        // issue next chunk's row gathers (hidden under the walk below)
        short8 rown[4];
        if (more) {
            #pragma unroll
            for (int p = 0; p < 4; ++p)
                rown[p] = *(const short8*)(efp + (long)idn[p].x * D + c8 * 8);
        }
        // strip walk: dword-col = tid&31 (2 f32 cols), 16-row strip
        {
            const int dwc = tid & 31;
            const int r0 = (tid >> 5) * 16;
            float seg0 = 0.f, seg1 = 0.f;
            int cur = dsts[r0];
            #pragma unroll 4
            for (int r = r0; r < r0 + 16; ++r) {
                int dv = dsts[r];
                unsigned u = Slds[r * 36 + dwc];
                if (dv != cur) {
                    if (cur >= 0) {
                        atomicAdd(nb_sum + (long)cur * D + 2 * dwc, seg0);
                        atomicAdd(nb_sum + (long)cur * D + 2 * dwc + 1, seg1);
                    }
                    seg0 = seg1 = 0.f;
                    cur = dv;
                }
                seg0 += b2f((ushort)(u & 0xffff));
                seg1 += b2f((ushort)(u >> 16));
            }
            if (cur >= 0) {
                atomicAdd(nb_sum + (long)cur * D + 2 * dwc, seg0);
                atomicAdd(nb_sum + (long)cur * D + 2 * dwc + 1, seg1);
            }
        }
        __syncthreads();
        if (!more) break;
        c = cn;
        #pragma unroll
        for (int p = 0; p < 4; ++p) { id[p] = idn[p]; row[p] = rown[p]; }
    }
}

// ---------------------------------------------------------------------------
// ndp_lite: ndp_b[n] = bf16( nb_sum[n]/max(deg,1) + nfp[n] ).  Elementwise.
// ---------------------------------------------------------------------------
__global__ __launch_bounds__(256) void ndp_lite_kernel(
    const float* __restrict__ nb_sum, const int* __restrict__ deg_i,
    const ushort* __restrict__ nfp_b, ushort* __restrict__ ndp_b, int N)
{
    long i = (long)blockIdx.x * 256 + threadIdx.x;   // group = (node, col-block)
    long node = i >> 3;
    int cb = (int)(i & 7);
    if (node >= N) return;
    float inv = 1.0f / fmaxf((float)deg_i[node], 1.0f);
    const float4* sp = (const float4*)(nb_sum + node * D + cb * 8);
    float4 x0 = sp[0], x1 = sp[1];
    short8 np = *(const short8*)(nfp_b + node * D + cb * 8);
    short8 r;
    r[0] = (short)f2b(x0.x * inv + b2f((ushort)np[0]));
    r[1] = (short)f2b(x0.y * inv + b2f((ushort)np[1]));
    r[2] = (short)f2b(x0.z * inv + b2f((ushort)np[2]));
    r[3] = (short)f2b(x0.w * inv + b2f((ushort)np[3]));
    r[4] = (short)f2b(x1.x * inv + b2f((ushort)np[4]));
    r[5] = (short)f2b(x1.y * inv + b2f((ushort)np[5]));
    r[6] = (short)f2b(x1.z * inv + b2f((ushort)np[6]));
    r[7] = (short)f2b(x1.w * inv + b2f((ushort)np[7]));
    *(short8*)(ndp_b + node * D + cb * 8) = r;
}

// ---------------------------------------------------------------------------
// final: ef_out = relu(efp + ndp[dst] + nfp[src] + bias2). Pure elementwise,
// nontemporal stores via ext-vector f32x4 (write-once 205 MB).
// ---------------------------------------------------------------------------
__global__ __launch_bounds__(256) void final_kernel(
    const ushort* __restrict__ efp, const int* __restrict__ src,
    const int* __restrict__ dst, const ushort* __restrict__ ndp_b,
    const ushort* __restrict__ nfp_b, const float* __restrict__ bias2,
    float* __restrict__ out, int E)
{
    long idx = (long)blockIdx.x * 256 + threadIdx.x;
    long e = idx >> 2;
    int q = (int)(idx & 3);
    if (e >= E) return;
    int dv = dst[e], sv = src[e];
    const short8* ep = (const short8*)(efp + e * D + q * 16);
    const short8* np = (const short8*)(ndp_b + (long)dv * D + q * 16);
    const short8* sp = (const short8*)(nfp_b + (long)sv * D + q * 16);
    short8 e0 = ep[0], e1 = ep[1];
    short8 n0 = np[0], n1 = np[1];
    short8 s0 = sp[0], s1 = sp[1];
    const float4* bp = (const float4*)(bias2 + q * 16);
    float4 b0 = bp[0], b1 = bp[1], b2 = bp[2], b3 = bp[3];

    float r[16];
    #pragma unroll
    for (int j = 0; j < 8; ++j) {
        r[j]     = b2f((ushort)e0[j]) + b2f((ushort)n0[j]) + b2f((ushort)s0[j]);
        r[8 + j] = b2f((ushort)e1[j]) + b2f((ushort)n1[j]) + b2f((ushort)s1[j]);
    }
    f32x4* op = (f32x4*)(out + e * D + q * 16);
    f32x4 o0 = {fmaxf(r[0] + b0.x, 0.f), fmaxf(r[1] + b0.y, 0.f),
                fmaxf(r[2] + b0.z, 0.f), fmaxf(r[3] + b0.w, 0.f)};
    f32x4 o1 = {fmaxf(r[4] + b1.x, 0.f), fmaxf(r[5] + b1.y, 0.f),
                fmaxf(r[6] + b1.z, 0.f), fmaxf(r[7] + b1.w, 0.f)};
    f32x4 o2 = {fmaxf(r[8] + b2.x, 0.f), fmaxf(r[9] + b2.y, 0.f),
                fmaxf(r[10] + b2.z, 0.f), fmaxf(r[11] + b2.w, 0.f)};
    f32x4 o3 = {fmaxf(r[12] + b3.x, 0.f), fmaxf(r[13] + b3.y, 0.f),
                fmaxf(r[14] + b3.z, 0.f), fmaxf(r[15] + b3.w, 0.f)};
    __builtin_nontemporal_store(o0, op + 0);
    __builtin_nontemporal_store(o1, op + 1);
    __builtin_nontemporal_store(o2, op + 2);
    __builtin_nontemporal_store(o3, op + 3);
}

// ---------------------------------------------------------------------------
extern "C" void kernel_launch(void* const* d_in, const int* in_sizes, int n_in,
                              void* d_out, int out_size, void* d_ws, size_t ws_size,
                              hipStream_t stream) {
    const float* nf        = (const float*)d_in[0];
    const float* ef        = (const float*)d_in[1];
    const int*   src       = (const int*)d_in[2];
    const int*   dst       = (const int*)d_in[3];
    const float* W_node    = (const float*)d_in[4];
    const float* W_edge    = (const float*)d_in[5];
    const float* bias_node = (const float*)d_in[6];
    const float* bias_edge = (const float*)d_in[7];
    const float* W_dense   = (const float*)d_in[8];
    const float* b_dense   = (const float*)d_in[9];

    const int N = in_sizes[0] / D;
    const int E = in_sizes[1] / D;
    const int NB = (N + 255) / 256;
    const int NPB = (N + 15) / 16;
    const int HB = (E + 255) / 256;

    float* nf_out = (float*)d_out;
    float* ef_out = (float*)d_out + (size_t)N * D;

    // ws layout: [zeroed: deg_i, nb_sum] then the rest
    char* p = (char*)d_ws;
    int*    deg_i    = (int*)p;     p += (size_t)N * 4;           // zeroed
    float*  nb_sum   = (float*)p;   p += (size_t)N * D * 4;       // zeroed, 12.8 MB
    size_t  zbytes   = (size_t)(p - (char*)d_ws);
    int*    pos      = (int*)p;     p += (size_t)N * 4;
    int*    cursor   = (int*)p;     p += (size_t)N * 4;
    int*    bsum     = (int*)p;     p += 256 * 4;
    int2*   sorted_ed= (int2*)p;    p += (size_t)E * 8;           // 6.4 MB
    ushort* nfp_b    = (ushort*)p;  p += (size_t)N * D * 2;
    ushort* ndp_b    = (ushort*)p;  p += (size_t)N * D * 2;
    ushort* Wcomb_b  = (ushort*)p;  p += D * D * 2;
    float*  bias2    = (float*)p;   p += 256;
    ushort* efp      = (ushort*)p;  /* E*D*2 = 102.4 MB */

    hipMemsetAsync(d_ws, 0, zbytes, stream);

    fused_front_kernel<<<NPB + HB + 1, 256, 0, stream>>>(
        nf, W_node, bias_node, W_dense, nf_out, nfp_b, N,
        dst, deg_i, E, W_edge, b_dense, bias_edge, Wcomb_b, bias2, NPB, HB);
    scanA_kernel<<<NB, 256, 0, stream>>>(deg_i, pos, bsum, N);
    scanB_kernel<<<1, 256, 0, stream>>>(bsum, NB);
    scanC_kernel<<<NB, 256, 0, stream>>>(pos, cursor, bsum, N);
    scatter_kernel<<<(E + 255) / 256, 256, 0, stream>>>(dst, cursor, sorted_ed, E);
    efp_stream_kernel<<<(E + 63) / 64, 256, 0, stream>>>(ef, Wcomb_b, efp, E);
    {
        const int nch = (E + SG_CH - 1) / SG_CH;
        const int grid = nch < 1024 ? nch : 1024;
        seg_gather_kernel<<<grid, 256, 0, stream>>>(efp, sorted_ed, nb_sum, E, nch, grid);
    }
    ndp_lite_kernel<<<(int)(((size_t)N * 8 + 255) / 256), 256, 0, stream>>>(
        nb_sum, deg_i, nfp_b, ndp_b, N);
    final_kernel<<<(int)(((size_t)E * 4 + 255) / 256), 256, 0, stream>>>(
        efp, src, dst, ndp_b, nfp_b, bias2, ef_out, E);
}

// Round 12
// 385.663 us; speedup vs baseline: 1.2022x; 1.2022x over previous
//
#include <hip/hip_runtime.h>

#define D 64

typedef __attribute__((ext_vector_type(8))) short short8;
typedef __attribute__((ext_vector_type(4))) float f32x4;

__device__ __forceinline__ ushort f2b(float f) {
    union { float f; unsigned u; } x; x.f = f;
    unsigned r = x.u + 0x7FFFu + ((x.u >> 16) & 1u);   // RNE to bf16
    return (ushort)(r >> 16);
}
__device__ __forceinline__ float b2f(ushort u) {
    union { float f; unsigned u; } x; x.u = ((unsigned)u) << 16;
    return x.f;
}
__device__ __forceinline__ short8 pack8(float4 a, float4 b) {
    short8 r;
    r[0] = (short)f2b(a.x); r[1] = (short)f2b(a.y); r[2] = (short)f2b(a.z); r[3] = (short)f2b(a.w);
    r[4] = (short)f2b(b.x); r[5] = (short)f2b(b.y); r[6] = (short)f2b(b.z); r[7] = (short)f2b(b.w);
    return r;
}

// ---------------------------------------------------------------------------
// fused_front: blocks [0, NPB)           -> node_proj + nfp
//              blocks [NPB, NPB+HB)      -> dst histogram
//              block  NPB+HB             -> Wcomb/bias2 setup
// ---------------------------------------------------------------------------
__global__ __launch_bounds__(256) void fused_front_kernel(
    const float* __restrict__ nf, const float* __restrict__ Wn,
    const float* __restrict__ bias, const float* __restrict__ Wd,   // full W_dense
    float* __restrict__ out, ushort* __restrict__ nfp_b, int N,
    const int* __restrict__ dst, int* __restrict__ deg_i, int E,
    const float* __restrict__ W_edge, const float* __restrict__ b_dense,
    const float* __restrict__ bias_edge, ushort* __restrict__ Wcomb_b,
    float* __restrict__ bias2, int NPB, int HB)
{
    __shared__ float Ws[D * D];
    __shared__ float Wb[D * D];
    __shared__ float As[16 * D];
    __shared__ float Vs[16 * D];
    const int tid = threadIdx.x;
    const int bid = blockIdx.x;

    if (bid < NPB) {
        constexpr int ROWS = 16;
        const long row0 = (long)bid * ROWS;
        const float* Wd_bot = Wd + D * D;
        #pragma unroll
        for (int i = tid; i < D * D / 4; i += 256) {
            ((float4*)Ws)[i] = ((const float4*)Wn)[i];
            float4 v = ((const float4*)Wd_bot)[i];
            ((float4*)Wb)[i] = make_float4(0.5f * v.x, 0.5f * v.y, 0.5f * v.z, 0.5f * v.w);
        }
        {
            int i = tid;  // ROWS*D/4 == 256
            long r = row0 + (i * 4) / D;
            ((float4*)As)[i] = (r < N) ? ((const float4*)nf)[row0 * D / 4 + i]
                                       : make_float4(0.f, 0.f, 0.f, 0.f);
        }
        __syncthreads();

        const int c = tid & 63;
        const float b = bias[c];
        for (int rr = tid >> 6; rr < ROWS; rr += 4) {
            float acc = 0.f;
            #pragma unroll
            for (int k = 0; k < D; ++k)
                acc = fmaf(As[rr * D + k], Ws[k * D + c], acc);
            float v = fmaxf(acc + b, 0.f);
            Vs[rr * D + c] = v;
            long r = row0 + rr;
            if (r < N) out[r * D + c] = v;
        }
        __syncthreads();
        for (int rr = tid >> 6; rr < ROWS; rr += 4) {
            float acc = 0.f;
            #pragma unroll
            for (int k = 0; k < D; ++k)
                acc = fmaf(Vs[rr * D + k], Wb[k * D + c], acc);
            long r = row0 + rr;
            if (r < N) nfp_b[r * D + c] = f2b(acc);
        }
    } else if (bid < NPB + HB) {
        int i = (bid - NPB) * 256 + tid;
        if (i < E) atomicAdd(deg_i + dst[i], 1);
    } else {
        // setup: Wcomb_b[n*64+k] = bf16((W_edge @ Wd_top)[k][n]); bias2
        for (int idx = tid; idx < D * D; idx += 256) {
            int k = idx >> 6, n = idx & 63;
            float s = 0.f;
            #pragma unroll 8
            for (int j = 0; j < D; ++j)
                s = fmaf(W_edge[k * D + j], Wd[j * D + n], s);
            Wcomb_b[n * D + k] = f2b(s);
        }
        if (tid < D) bias2[tid] = b_dense[tid] + bias_edge[tid];
    }
}

// ---------------------------------------------------------------------------
// Counting sort of edges by dst: (hist in fused_front) -> scan x3 -> scatter
// ---------------------------------------------------------------------------
__global__ __launch_bounds__(256) void scanA_kernel(
    const int* __restrict__ deg_i, int* __restrict__ pos,
    int* __restrict__ bsum, int N)
{
    __shared__ int s[256];
    const int tid = threadIdx.x;
    const int i = blockIdx.x * 256 + tid;
    int v = (i < N) ? deg_i[i] : 0;
    s[tid] = v;
    __syncthreads();
    #pragma unroll
    for (int off = 1; off < 256; off <<= 1) {
        int t = (tid >= off) ? s[tid - off] : 0;
        __syncthreads();
        s[tid] += t;
        __syncthreads();
    }
    if (i < N) pos[i] = s[tid] - v;          // block-local exclusive
    if (tid == 255) bsum[blockIdx.x] = s[255];
}

__global__ __launch_bounds__(256) void scanB_kernel(int* __restrict__ bsum, int NB)
{
    __shared__ int s[256];
    const int tid = threadIdx.x;
    int v = (tid < NB) ? bsum[tid] : 0;
    s[tid] = v;
    __syncthreads();
    #pragma unroll
    for (int off = 1; off < 256; off <<= 1) {
        int t = (tid >= off) ? s[tid - off] : 0;
        __syncthreads();
        s[tid] += t;
        __syncthreads();
    }
    if (tid < NB) bsum[tid] = s[tid] - v;    // exclusive
}

__global__ __launch_bounds__(256) void scanC_kernel(
    const int* __restrict__ pos, int* __restrict__ cursor,
    const int* __restrict__ bsum, int N)
{
    int i = blockIdx.x * 256 + threadIdx.x;
    if (i < N) cursor[i] = pos[i] + bsum[blockIdx.x];
}

__global__ __launch_bounds__(256) void scatter_kernel(
    const int* __restrict__ dst, int* __restrict__ cursor,
    int2* __restrict__ sorted_ed, int E)
{
    int i = blockIdx.x * 256 + threadIdx.x;
    if (i < E) {
        int dv = dst[i];
        int slot = atomicAdd(cursor + dv, 1);
        sorted_ed[slot] = make_int2(i, dv);
    }
}

// ---------------------------------------------------------------------------
// efp_seg (round-9 proven): 128 dst-sorted edges per block (2 MFMA tiles).
// Per-lane sorted_ed loads; ef-row gathers -> MFMA -> packed bf16 dwords
// stored to efp (natural layout) and a bf16 LDS tile; one barrier;
// 256-thread parallel segment walk -> f32 atomics into nb_sum.
// ---------------------------------------------------------------------------
#define SEG_ROWS 128
__global__ __launch_bounds__(256) void efp_seg_kernel(
    const float* __restrict__ ef, const int2* __restrict__ sorted_ed,
    const ushort* __restrict__ Wt, ushort* __restrict__ efp,
    float* __restrict__ nb_sum, int E)
{
    __shared__ unsigned Slds[SEG_ROWS * 33];   // packed bf16 pairs, 16896 B
    __shared__ int dsts[SEG_ROWS];
    const int tid = threadIdx.x;
    const long s0 = (long)blockIdx.x * SEG_ROWS;

    const int w = tid >> 6, lane = tid & 63;
    const int lr = lane & 15, g = lane >> 4;
    const bool odd = lane & 1;

    // gather-row eids (per-lane, no LDS dependency)
    long gde[2];
    #pragma unroll
    for (int tt = 0; tt < 2; ++tt) {
        long s = s0 + 64 * tt + 16 * w + lr;
        if (s >= E) s = E - 1;
        gde[tt] = (long)sorted_ed[s].x;
    }
    // issue all ef gathers
    float4 va[2][4];
    #pragma unroll
    for (int tt = 0; tt < 2; ++tt) {
        const float4* ap = (const float4*)(ef + gde[tt] * D);
        va[tt][0] = ap[2 * g];     va[tt][1] = ap[2 * g + 1];
        va[tt][2] = ap[8 + 2 * g]; va[tt][3] = ap[8 + 2 * g + 1];
    }
    // store-row eids: int4 covers sorted_ed[rb] and [rb+1] (rb even)
    int rbl[2]; long seo[2][2];
    #pragma unroll
    for (int tt = 0; tt < 2; ++tt) {
        rbl[tt] = 64 * tt + 16 * w + 4 * g + (odd ? 2 : 0);
        long s = s0 + rbl[tt];
        if (s > E - 2) s = (E - 2) & ~1L;
        int4 q = *(const int4*)&sorted_ed[s];
        seo[tt][0] = (long)q.x * D;
        seo[tt][1] = (long)q.z * D;
    }
    // dsts for the walk
    if (tid < SEG_ROWS) {
        long s = s0 + tid;
        dsts[tid] = (s < E) ? sorted_ed[s].y : -1;
    }

    // B fragments (L1-resident)
    short8 bf0[4], bf1[4];
    #pragma unroll
    for (int t = 0; t < 4; ++t) {
        bf0[t] = *(const short8*)&Wt[(16 * t + lr) * D + 8 * g];
        bf1[t] = *(const short8*)&Wt[(16 * t + lr) * D + 32 + 8 * g];
    }

    #pragma unroll
    for (int tt = 0; tt < 2; ++tt) {
        short8 a0 = pack8(va[tt][0], va[tt][1]);
        short8 a1 = pack8(va[tt][2], va[tt][3]);
        f32x4 acc[4];
        #pragma unroll
        for (int t = 0; t < 4; ++t) {
            f32x4 z = {0.f, 0.f, 0.f, 0.f};
            z = __builtin_amdgcn_mfma_f32_16x16x32_bf16(a0, bf0[t], z, 0, 0, 0);
            z = __builtin_amdgcn_mfma_f32_16x16x32_bf16(a1, bf1[t], z, 0, 0, 0);
            acc[t] = z;
        }

        const int rb = rbl[tt];
        long sl0 = s0 + rb, sl1 = s0 + rb + 1;
        #pragma unroll
        for (int t = 0; t < 4; ++t) {
            float p0 = __shfl_xor(acc[t][0], 1, 64);
            float p1 = __shfl_xor(acc[t][1], 1, 64);
            float p2 = __shfl_xor(acc[t][2], 1, 64);
            float p3 = __shfl_xor(acc[t][3], 1, 64);
            float lo0, hi0, lo1, hi1;
            if (odd) { lo0 = p2; hi0 = acc[t][2]; lo1 = p3; hi1 = acc[t][3]; }
            else     { lo0 = acc[t][0]; hi0 = p0; lo1 = acc[t][1]; hi1 = p1; }
            int cbase = 16 * t + (lr & ~1);
            int dc = cbase >> 1;
            unsigned dw0 = ((unsigned)f2b(hi0) << 16) | (unsigned)f2b(lo0);
            unsigned dw1 = ((unsigned)f2b(hi1) << 16) | (unsigned)f2b(lo1);
            if (sl0 < E) *(unsigned*)(efp + seo[tt][0] + cbase) = dw0;
            if (sl1 < E) *(unsigned*)(efp + seo[tt][1] + cbase) = dw1;
            Slds[rb * 33 + dc]       = dw0;
            Slds[(rb + 1) * 33 + dc] = dw1;
        }
    }
    __syncthreads();

    // parallel segment walk: dword-col = tid&31 (2 f32 cols), strip of 16 rows.
    {
        const int dwc = tid & 31;
        const int r0 = (tid >> 5) * 16;
        float seg0 = 0.f, seg1 = 0.f;
        int cur = dsts[r0];
        #pragma unroll 4
        for (int r = r0; r < r0 + 16; ++r) {
            int dv = dsts[r];
            unsigned u = Slds[r * 33 + dwc];
            if (dv != cur) {
                if (cur >= 0) {
                    atomicAdd(nb_sum + (long)cur * D + 2 * dwc, seg0);
                    atomicAdd(nb_sum + (long)cur * D + 2 * dwc + 1, seg1);
                }
                seg0 = seg1 = 0.f;
                cur = dv;
            }
            seg0 += b2f((ushort)(u & 0xffff));
            seg1 += b2f((ushort)(u >> 16));
        }
        if (cur >= 0) {
            atomicAdd(nb_sum + (long)cur * D + 2 * dwc, seg0);
            atomicAdd(nb_sum + (long)cur * D + 2 * dwc + 1, seg1);
        }
    }
}

// ---------------------------------------------------------------------------
// ndp_lite: ndp_b[n] = bf16( nb_sum[n]/max(deg,1) + nfp[n] ).  Elementwise.
// ---------------------------------------------------------------------------
__global__ __launch_bounds__(256) void ndp_lite_kernel(
    const float* __restrict__ nb_sum, const int* __restrict__ deg_i,
    const ushort* __restrict__ nfp_b, ushort* __restrict__ ndp_b, int N)
{
    long i = (long)blockIdx.x * 256 + threadIdx.x;   // group = (node, col-block)
    long node = i >> 3;
    int cb = (int)(i & 7);
    if (node >= N) return;
    float inv = 1.0f / fmaxf((float)deg_i[node], 1.0f);
    const float4* sp = (const float4*)(nb_sum + node * D + cb * 8);
    float4 x0 = sp[0], x1 = sp[1];
    short8 np = *(const short8*)(nfp_b + node * D + cb * 8);
    short8 r;
    r[0] = (short)f2b(x0.x * inv + b2f((ushort)np[0]));
    r[1] = (short)f2b(x0.y * inv + b2f((ushort)np[1]));
    r[2] = (short)f2b(x0.z * inv + b2f((ushort)np[2]));
    r[3] = (short)f2b(x0.w * inv + b2f((ushort)np[3]));
    r[4] = (short)f2b(x1.x * inv + b2f((ushort)np[4]));
    r[5] = (short)f2b(x1.y * inv + b2f((ushort)np[5]));
    r[6] = (short)f2b(x1.z * inv + b2f((ushort)np[6]));
    r[7] = (short)f2b(x1.w * inv + b2f((ushort)np[7]));
    *(short8*)(ndp_b + node * D + cb * 8) = r;
}

// ---------------------------------------------------------------------------
// final: ef_out = relu(efp + ndp[dst] + nfp[src] + bias2). Pure elementwise,
// plain float4 stores (NT stores measured −40µs regression, round 11).
// ---------------------------------------------------------------------------
__global__ __launch_bounds__(256) void final_kernel(
    const ushort* __restrict__ efp, const int* __restrict__ src,
    const int* __restrict__ dst, const ushort* __restrict__ ndp_b,
    const ushort* __restrict__ nfp_b, const float* __restrict__ bias2,
    float* __restrict__ out, int E)
{
    long idx = (long)blockIdx.x * 256 + threadIdx.x;
    long e = idx >> 2;
    int q = (int)(idx & 3);
    if (e >= E) return;
    int dv = dst[e], sv = src[e];
    const short8* ep = (const short8*)(efp + e * D + q * 16);
    const short8* np = (const short8*)(ndp_b + (long)dv * D + q * 16);
    const short8* sp = (const short8*)(nfp_b + (long)sv * D + q * 16);
    short8 e0 = ep[0], e1 = ep[1];
    short8 n0 = np[0], n1 = np[1];
    short8 s0 = sp[0], s1 = sp[1];
    const float4* bp = (const float4*)(bias2 + q * 16);
    float4 b0 = bp[0], b1 = bp[1], b2 = bp[2], b3 = bp[3];

    float r[16];
    #pragma unroll
    for (int j = 0; j < 8; ++j) {
        r[j]     = b2f((ushort)e0[j]) + b2f((ushort)n0[j]) + b2f((ushort)s0[j]);
        r[8 + j] = b2f((ushort)e1[j]) + b2f((ushort)n1[j]) + b2f((ushort)s1[j]);
    }
    float4* op = (float4*)(out + e * D + q * 16);
    op[0] = make_float4(fmaxf(r[0] + b0.x, 0.f), fmaxf(r[1] + b0.y, 0.f),
                        fmaxf(r[2] + b0.z, 0.f), fmaxf(r[3] + b0.w, 0.f));
    op[1] = make_float4(fmaxf(r[4] + b1.x, 0.f), fmaxf(r[5] + b1.y, 0.f),
                        fmaxf(r[6] + b1.z, 0.f), fmaxf(r[7] + b1.w, 0.f));
    op[2] = make_float4(fmaxf(r[8] + b2.x, 0.f), fmaxf(r[9] + b2.y, 0.f),
                        fmaxf(r[10] + b2.z, 0.f), fmaxf(r[11] + b2.w, 0.f));
    op[3] = make_float4(fmaxf(r[12] + b3.x, 0.f), fmaxf(r[13] + b3.y, 0.f),
                        fmaxf(r[14] + b3.z, 0.f), fmaxf(r[15] + b3.w, 0.f));
}

// ---------------------------------------------------------------------------
extern "C" void kernel_launch(void* const* d_in, const int* in_sizes, int n_in,
                              void* d_out, int out_size, void* d_ws, size_t ws_size,
                              hipStream_t stream) {
    const float* nf        = (const float*)d_in[0];
    const float* ef        = (const float*)d_in[1];
    const int*   src       = (const int*)d_in[2];
    const int*   dst       = (const int*)d_in[3];
    const float* W_node    = (const float*)d_in[4];
    const float* W_edge    = (const float*)d_in[5];
    const float* bias_node = (const float*)d_in[6];
    const float* bias_edge = (const float*)d_in[7];
    const float* W_dense   = (const float*)d_in[8];
    const float* b_dense   = (const float*)d_in[9];

    const int N = in_sizes[0] / D;
    const int E = in_sizes[1] / D;
    const int NB = (N + 255) / 256;
    const int NPB = (N + 15) / 16;
    const int HB = (E + 255) / 256;

    float* nf_out = (float*)d_out;
    float* ef_out = (float*)d_out + (size_t)N * D;

    // ws layout: [zeroed: deg_i, nb_sum] then the rest
    char* p = (char*)d_ws;
    int*    deg_i    = (int*)p;     p += (size_t)N * 4;           // zeroed
    float*  nb_sum   = (float*)p;   p += (size_t)N * D * 4;       // zeroed, 12.8 MB
    size_t  zbytes   = (size_t)(p - (char*)d_ws);
    int*    pos      = (int*)p;     p += (size_t)N * 4;
    int*    cursor   = (int*)p;     p += (size_t)N * 4;
    int*    bsum     = (int*)p;     p += 256 * 4;
    int2*   sorted_ed= (int2*)p;    p += (size_t)E * 8;           // 6.4 MB
    ushort* nfp_b    = (ushort*)p;  p += (size_t)N * D * 2;
    ushort* ndp_b    = (ushort*)p;  p += (size_t)N * D * 2;
    ushort* Wcomb_b  = (ushort*)p;  p += D * D * 2;
    float*  bias2    = (float*)p;   p += 256;
    ushort* efp      = (ushort*)p;  /* E*D*2 = 102.4 MB */

    hipMemsetAsync(d_ws, 0, zbytes, stream);

    fused_front_kernel<<<NPB + HB + 1, 256, 0, stream>>>(
        nf, W_node, bias_node, W_dense, nf_out, nfp_b, N,
        dst, deg_i, E, W_edge, b_dense, bias_edge, Wcomb_b, bias2, NPB, HB);
    scanA_kernel<<<NB, 256, 0, stream>>>(deg_i, pos, bsum, N);
    scanB_kernel<<<1, 256, 0, stream>>>(bsum, NB);
    scanC_kernel<<<NB, 256, 0, stream>>>(pos, cursor, bsum, N);
    scatter_kernel<<<(E + 255) / 256, 256, 0, stream>>>(dst, cursor, sorted_ed, E);
    efp_seg_kernel<<<(E + SEG_ROWS - 1) / SEG_ROWS, 256, 0, stream>>>(
        ef, sorted_ed, Wcomb_b, efp, nb_sum, E);
    ndp_lite_kernel<<<(int)(((size_t)N * 8 + 255) / 256), 256, 0, stream>>>(
        nb_sum, deg_i, nfp_b, ndp_b, N);
    final_kernel<<<(int)(((size_t)E * 4 + 255) / 256), 256, 0, stream>>>(
        efp, src, dst, ndp_b, nfp_b, bias2, ef_out, E);
}

// Round 13
// 379.394 us; speedup vs baseline: 1.2220x; 1.0165x over previous
//
#include <hip/hip_runtime.h>

#define D 64

typedef __attribute__((ext_vector_type(8))) short short8;
typedef __attribute__((ext_vector_type(4))) float f32x4;

__device__ __forceinline__ ushort f2b(float f) {
    union { float f; unsigned u; } x; x.f = f;
    unsigned r = x.u + 0x7FFFu + ((x.u >> 16) & 1u);   // RNE to bf16
    return (ushort)(r >> 16);
}
__device__ __forceinline__ float b2f(ushort u) {
    union { float f; unsigned u; } x; x.u = ((unsigned)u) << 16;
    return x.f;
}
__device__ __forceinline__ short8 pack8(float4 a, float4 b) {
    short8 r;
    r[0] = (short)f2b(a.x); r[1] = (short)f2b(a.y); r[2] = (short)f2b(a.z); r[3] = (short)f2b(a.w);
    r[4] = (short)f2b(b.x); r[5] = (short)f2b(b.y); r[6] = (short)f2b(b.z); r[7] = (short)f2b(b.w);
    return r;
}

// ---------------------------------------------------------------------------
// fused_front: blocks [0, NPB)           -> node_proj + nfp
//              blocks [NPB, NPB+HB)      -> dst histogram
//              block  NPB+HB             -> Wcomb/bias2 setup
// ---------------------------------------------------------------------------
__global__ __launch_bounds__(256) void fused_front_kernel(
    const float* __restrict__ nf, const float* __restrict__ Wn,
    const float* __restrict__ bias, const float* __restrict__ Wd,   // full W_dense
    float* __restrict__ out, ushort* __restrict__ nfp_b, int N,
    const int* __restrict__ dst, int* __restrict__ deg_i, int E,
    const float* __restrict__ W_edge, const float* __restrict__ b_dense,
    const float* __restrict__ bias_edge, ushort* __restrict__ Wcomb_b,
    float* __restrict__ bias2, int NPB, int HB)
{
    __shared__ float Ws[D * D];
    __shared__ float Wb[D * D];
    __shared__ float As[16 * D];
    __shared__ float Vs[16 * D];
    const int tid = threadIdx.x;
    const int bid = blockIdx.x;

    if (bid < NPB) {
        constexpr int ROWS = 16;
        const long row0 = (long)bid * ROWS;
        const float* Wd_bot = Wd + D * D;
        #pragma unroll
        for (int i = tid; i < D * D / 4; i += 256) {
            ((float4*)Ws)[i] = ((const float4*)Wn)[i];
            float4 v = ((const float4*)Wd_bot)[i];
            ((float4*)Wb)[i] = make_float4(0.5f * v.x, 0.5f * v.y, 0.5f * v.z, 0.5f * v.w);
        }
        {
            int i = tid;  // ROWS*D/4 == 256
            long r = row0 + (i * 4) / D;
            ((float4*)As)[i] = (r < N) ? ((const float4*)nf)[row0 * D / 4 + i]
                                       : make_float4(0.f, 0.f, 0.f, 0.f);
        }
        __syncthreads();

        const int c = tid & 63;
        const float b = bias[c];
        for (int rr = tid >> 6; rr < ROWS; rr += 4) {
            float acc = 0.f;
            #pragma unroll
            for (int k = 0; k < D; ++k)
                acc = fmaf(As[rr * D + k], Ws[k * D + c], acc);
            float v = fmaxf(acc + b, 0.f);
            Vs[rr * D + c] = v;
            long r = row0 + rr;
            if (r < N) out[r * D + c] = v;
        }
        __syncthreads();
        for (int rr = tid >> 6; rr < ROWS; rr += 4) {
            float acc = 0.f;
            #pragma unroll
            for (int k = 0; k < D; ++k)
                acc = fmaf(Vs[rr * D + k], Wb[k * D + c], acc);
            long r = row0 + rr;
            if (r < N) nfp_b[r * D + c] = f2b(acc);
        }
    } else if (bid < NPB + HB) {
        int i = (bid - NPB) * 256 + tid;
        if (i < E) atomicAdd(deg_i + dst[i], 1);
    } else {
        // setup: Wcomb_b[n*64+k] = bf16((W_edge @ Wd_top)[k][n]); bias2
        for (int idx = tid; idx < D * D; idx += 256) {
            int k = idx >> 6, n = idx & 63;
            float s = 0.f;
            #pragma unroll 8
            for (int j = 0; j < D; ++j)
                s = fmaf(W_edge[k * D + j], Wd[j * D + n], s);
            Wcomb_b[n * D + k] = f2b(s);
        }
        if (tid < D) bias2[tid] = b_dense[tid] + bias_edge[tid];
    }
}

// ---------------------------------------------------------------------------
// Counting sort of edges by dst: (hist in fused_front) -> scan x3 -> scatter
// ---------------------------------------------------------------------------
__global__ __launch_bounds__(256) void scanA_kernel(
    const int* __restrict__ deg_i, int* __restrict__ pos,
    int* __restrict__ bsum, int N)
{
    __shared__ int s[256];
    const int tid = threadIdx.x;
    const int i = blockIdx.x * 256 + tid;
    int v = (i < N) ? deg_i[i] : 0;
    s[tid] = v;
    __syncthreads();
    #pragma unroll
    for (int off = 1; off < 256; off <<= 1) {
        int t = (tid >= off) ? s[tid - off] : 0;
        __syncthreads();
        s[tid] += t;
        __syncthreads();
    }
    if (i < N) pos[i] = s[tid] - v;          // block-local exclusive
    if (tid == 255) bsum[blockIdx.x] = s[255];
}

__global__ __launch_bounds__(256) void scanB_kernel(int* __restrict__ bsum, int NB)
{
    __shared__ int s[256];
    const int tid = threadIdx.x;
    int v = (tid < NB) ? bsum[tid] : 0;
    s[tid] = v;
    __syncthreads();
    #pragma unroll
    for (int off = 1; off < 256; off <<= 1) {
        int t = (tid >= off) ? s[tid - off] : 0;
        __syncthreads();
        s[tid] += t;
        __syncthreads();
    }
    if (tid < NB) bsum[tid] = s[tid] - v;    // exclusive
}

__global__ __launch_bounds__(256) void scanC_kernel(
    const int* __restrict__ pos, int* __restrict__ cursor,
    const int* __restrict__ bsum, int N)
{
    int i = blockIdx.x * 256 + threadIdx.x;
    if (i < N) cursor[i] = pos[i] + bsum[blockIdx.x];
}

__global__ __launch_bounds__(256) void scatter_kernel(
    const int* __restrict__ dst, int* __restrict__ cursor,
    int2* __restrict__ sorted_ed, int E)
{
    int i = blockIdx.x * 256 + threadIdx.x;
    if (i < E) {
        int dv = dst[i];
        int slot = atomicAdd(cursor + dv, 1);
        sorted_ed[slot] = make_int2(i, dv);
    }
}

// ---------------------------------------------------------------------------
// efp_seg: 256 dst-sorted edges per block (4 MFMA tiles), 4 waves.
// All 16 ef-row gather loads issued up front per lane; MFMA -> packed bf16
// dwords stored to efp (natural layout) AND a bf16 LDS tile (stride 34 dwords
// -> conflict-free: bank = (2*rb+dc)&31 is uniform 2-way); one barrier;
// 256-thread parallel segment walk (32-row strip x dword-col) -> f32 atomics.
// LDS 35.8 KB -> 4 blocks/CU (matches VGPR limit).
// ---------------------------------------------------------------------------
#define SEG_ROWS 256
#define SLSTR 34
__global__ __launch_bounds__(256) void efp_seg_kernel(
    const float* __restrict__ ef, const int2* __restrict__ sorted_ed,
    const ushort* __restrict__ Wt, ushort* __restrict__ efp,
    float* __restrict__ nb_sum, int E)
{
    __shared__ unsigned Slds[SEG_ROWS * SLSTR];   // 34816 B
    __shared__ int dsts[SEG_ROWS];                // 1024 B
    const int tid = threadIdx.x;
    const long s0 = (long)blockIdx.x * SEG_ROWS;

    const int w = tid >> 6, lane = tid & 63;
    const int lr = lane & 15, g = lane >> 4;
    const bool odd = lane & 1;

    // gather-row eids (per-lane, no LDS dependency)
    long gde[4];
    #pragma unroll
    for (int tt = 0; tt < 4; ++tt) {
        long s = s0 + 64 * tt + 16 * w + lr;
        if (s >= E) s = E - 1;
        gde[tt] = (long)sorted_ed[s].x;
    }
    // issue ALL ef gathers (16 dwordx4 per lane outstanding)
    float4 va[4][4];
    #pragma unroll
    for (int tt = 0; tt < 4; ++tt) {
        const float4* ap = (const float4*)(ef + gde[tt] * D);
        va[tt][0] = ap[2 * g];     va[tt][1] = ap[2 * g + 1];
        va[tt][2] = ap[8 + 2 * g]; va[tt][3] = ap[8 + 2 * g + 1];
    }
    // store-row eids: int4 covers sorted_ed[rb] and [rb+1] (rb even)
    int rbl[4]; long seo[4][2];
    #pragma unroll
    for (int tt = 0; tt < 4; ++tt) {
        rbl[tt] = 64 * tt + 16 * w + 4 * g + (odd ? 2 : 0);
        long s = s0 + rbl[tt];
        if (s > E - 2) s = (E - 2) & ~1L;
        int4 q = *(const int4*)&sorted_ed[s];
        seo[tt][0] = (long)q.x * D;
        seo[tt][1] = (long)q.z * D;
    }
    // dsts for the walk (one per thread)
    {
        long s = s0 + tid;
        dsts[tid] = (s < E) ? sorted_ed[s].y : -1;
    }

    // B fragments (L1-resident)
    short8 bf0[4], bf1[4];
    #pragma unroll
    for (int t = 0; t < 4; ++t) {
        bf0[t] = *(const short8*)&Wt[(16 * t + lr) * D + 8 * g];
        bf1[t] = *(const short8*)&Wt[(16 * t + lr) * D + 32 + 8 * g];
    }

    #pragma unroll
    for (int tt = 0; tt < 4; ++tt) {
        short8 a0 = pack8(va[tt][0], va[tt][1]);
        short8 a1 = pack8(va[tt][2], va[tt][3]);
        f32x4 acc[4];
        #pragma unroll
        for (int t = 0; t < 4; ++t) {
            f32x4 z = {0.f, 0.f, 0.f, 0.f};
            z = __builtin_amdgcn_mfma_f32_16x16x32_bf16(a0, bf0[t], z, 0, 0, 0);
            z = __builtin_amdgcn_mfma_f32_16x16x32_bf16(a1, bf1[t], z, 0, 0, 0);
            acc[t] = z;
        }

        const int rb = rbl[tt];
        long sl0 = s0 + rb, sl1 = s0 + rb + 1;
        #pragma unroll
        for (int t = 0; t < 4; ++t) {
            float p0 = __shfl_xor(acc[t][0], 1, 64);
            float p1 = __shfl_xor(acc[t][1], 1, 64);
            float p2 = __shfl_xor(acc[t][2], 1, 64);
            float p3 = __shfl_xor(acc[t][3], 1, 64);
            float lo0, hi0, lo1, hi1;
            if (odd) { lo0 = p2; hi0 = acc[t][2]; lo1 = p3; hi1 = acc[t][3]; }
            else     { lo0 = acc[t][0]; hi0 = p0; lo1 = acc[t][1]; hi1 = p1; }
            int cbase = 16 * t + (lr & ~1);
            int dc = cbase >> 1;
            unsigned dw0 = ((unsigned)f2b(hi0) << 16) | (unsigned)f2b(lo0);
            unsigned dw1 = ((unsigned)f2b(hi1) << 16) | (unsigned)f2b(lo1);
            if (sl0 < E) *(unsigned*)(efp + seo[tt][0] + cbase) = dw0;
            if (sl1 < E) *(unsigned*)(efp + seo[tt][1] + cbase) = dw1;
            Slds[rb * SLSTR + dc]       = dw0;
            Slds[(rb + 1) * SLSTR + dc] = dw1;
        }
    }
    __syncthreads();

    // parallel segment walk: dword-col = tid&31 (2 f32 cols), strip of 32 rows.
    {
        const int dwc = tid & 31;
        const int r0 = (tid >> 5) * 32;
        float seg0 = 0.f, seg1 = 0.f;
        int cur = dsts[r0];
        #pragma unroll 4
        for (int r = r0; r < r0 + 32; ++r) {
            int dv = dsts[r];
            unsigned u = Slds[r * SLSTR + dwc];
            if (dv != cur) {
                if (cur >= 0) {
                    atomicAdd(nb_sum + (long)cur * D + 2 * dwc, seg0);
                    atomicAdd(nb_sum + (long)cur * D + 2 * dwc + 1, seg1);
                }
                seg0 = seg1 = 0.f;
                cur = dv;
            }
            seg0 += b2f((ushort)(u & 0xffff));
            seg1 += b2f((ushort)(u >> 16));
        }
        if (cur >= 0) {
            atomicAdd(nb_sum + (long)cur * D + 2 * dwc, seg0);
            atomicAdd(nb_sum + (long)cur * D + 2 * dwc + 1, seg1);
        }
    }
}

// ---------------------------------------------------------------------------
// ndp_lite: ndp_b[n] = bf16( nb_sum[n]/max(deg,1) + nfp[n] ).  Elementwise.
// ---------------------------------------------------------------------------
__global__ __launch_bounds__(256) void ndp_lite_kernel(
    const float* __restrict__ nb_sum, const int* __restrict__ deg_i,
    const ushort* __restrict__ nfp_b, ushort* __restrict__ ndp_b, int N)
{
    long i = (long)blockIdx.x * 256 + threadIdx.x;   // group = (node, col-block)
    long node = i >> 3;
    int cb = (int)(i & 7);
    if (node >= N) return;
    float inv = 1.0f / fmaxf((float)deg_i[node], 1.0f);
    const float4* sp = (const float4*)(nb_sum + node * D + cb * 8);
    float4 x0 = sp[0], x1 = sp[1];
    short8 np = *(const short8*)(nfp_b + node * D + cb * 8);
    short8 r;
    r[0] = (short)f2b(x0.x * inv + b2f((ushort)np[0]));
    r[1] = (short)f2b(x0.y * inv + b2f((ushort)np[1]));
    r[2] = (short)f2b(x0.z * inv + b2f((ushort)np[2]));
    r[3] = (short)f2b(x0.w * inv + b2f((ushort)np[3]));
    r[4] = (short)f2b(x1.x * inv + b2f((ushort)np[4]));
    r[5] = (short)f2b(x1.y * inv + b2f((ushort)np[5]));
    r[6] = (short)f2b(x1.z * inv + b2f((ushort)np[6]));
    r[7] = (short)f2b(x1.w * inv + b2f((ushort)np[7]));
    *(short8*)(ndp_b + node * D + cb * 8) = r;
}

// ---------------------------------------------------------------------------
// final: ef_out = relu(efp + ndp[dst] + nfp[src] + bias2). Pure elementwise,
// plain float4 stores (NT stores measured -40us regression, round 11).
// ---------------------------------------------------------------------------
__global__ __launch_bounds__(256) void final_kernel(
    const ushort* __restrict__ efp, const int* __restrict__ src,
    const int* __restrict__ dst, const ushort* __restrict__ ndp_b,
    const ushort* __restrict__ nfp_b, const float* __restrict__ bias2,
    float* __restrict__ out, int E)
{
    long idx = (long)blockIdx.x * 256 + threadIdx.x;
    long e = idx >> 2;
    int q = (int)(idx & 3);
    if (e >= E) return;
    int dv = dst[e], sv = src[e];
    const short8* ep = (const short8*)(efp + e * D + q * 16);
    const short8* np = (const short8*)(ndp_b + (long)dv * D + q * 16);
    const short8* sp = (const short8*)(nfp_b + (long)sv * D + q * 16);
    short8 e0 = ep[0], e1 = ep[1];
    short8 n0 = np[0], n1 = np[1];
    short8 s0 = sp[0], s1 = sp[1];
    const float4* bp = (const float4*)(bias2 + q * 16);
    float4 b0 = bp[0], b1 = bp[1], b2 = bp[2], b3 = bp[3];

    float r[16];
    #pragma unroll
    for (int j = 0; j < 8; ++j) {
        r[j]     = b2f((ushort)e0[j]) + b2f((ushort)n0[j]) + b2f((ushort)s0[j]);
        r[8 + j] = b2f((ushort)e1[j]) + b2f((ushort)n1[j]) + b2f((ushort)s1[j]);
    }
    float4* op = (float4*)(out + e * D + q * 16);
    op[0] = make_float4(fmaxf(r[0] + b0.x, 0.f), fmaxf(r[1] + b0.y, 0.f),
                        fmaxf(r[2] + b0.z, 0.f), fmaxf(r[3] + b0.w, 0.f));
    op[1] = make_float4(fmaxf(r[4] + b1.x, 0.f), fmaxf(r[5] + b1.y, 0.f),
                        fmaxf(r[6] + b1.z, 0.f), fmaxf(r[7] + b1.w, 0.f));
    op[2] = make_float4(fmaxf(r[8] + b2.x, 0.f), fmaxf(r[9] + b2.y, 0.f),
                        fmaxf(r[10] + b2.z, 0.f), fmaxf(r[11] + b2.w, 0.f));
    op[3] = make_float4(fmaxf(r[12] + b3.x, 0.f), fmaxf(r[13] + b3.y, 0.f),
                        fmaxf(r[14] + b3.z, 0.f), fmaxf(r[15] + b3.w, 0.f));
}

// ---------------------------------------------------------------------------
extern "C" void kernel_launch(void* const* d_in, const int* in_sizes, int n_in,
                              void* d_out, int out_size, void* d_ws, size_t ws_size,
                              hipStream_t stream) {
    const float* nf        = (const float*)d_in[0];
    const float* ef        = (const float*)d_in[1];
    const int*   src       = (const int*)d_in[2];
    const int*   dst       = (const int*)d_in[3];
    const float* W_node    = (const float*)d_in[4];
    const float* W_edge    = (const float*)d_in[5];
    const float* bias_node = (const float*)d_in[6];
    const float* bias_edge = (const float*)d_in[7];
    const float* W_dense   = (const float*)d_in[8];
    const float* b_dense   = (const float*)d_in[9];

    const int N = in_sizes[0] / D;
    const int E = in_sizes[1] / D;
    const int NB = (N + 255) / 256;
    const int NPB = (N + 15) / 16;
    const int HB = (E + 255) / 256;

    float* nf_out = (float*)d_out;
    float* ef_out = (float*)d_out + (size_t)N * D;

    // ws layout: [zeroed: deg_i, nb_sum] then the rest
    char* p = (char*)d_ws;
    int*    deg_i    = (int*)p;     p += (size_t)N * 4;           // zeroed
    float*  nb_sum   = (float*)p;   p += (size_t)N * D * 4;       // zeroed, 12.8 MB
    size_t  zbytes   = (size_t)(p - (char*)d_ws);
    int*    pos      = (int*)p;     p += (size_t)N * 4;
    int*    cursor   = (int*)p;     p += (size_t)N * 4;
    int*    bsum     = (int*)p;     p += 256 * 4;
    int2*   sorted_ed= (int2*)p;    p += (size_t)E * 8;           // 6.4 MB
    ushort* nfp_b    = (ushort*)p;  p += (size_t)N * D * 2;
    ushort* ndp_b    = (ushort*)p;  p += (size_t)N * D * 2;
    ushort* Wcomb_b  = (ushort*)p;  p += D * D * 2;
    float*  bias2    = (float*)p;   p += 256;
    ushort* efp      = (ushort*)p;  /* E*D*2 = 102.4 MB */

    hipMemsetAsync(d_ws, 0, zbytes, stream);

    fused_front_kernel<<<NPB + HB + 1, 256, 0, stream>>>(
        nf, W_node, bias_node, W_dense, nf_out, nfp_b, N,
        dst, deg_i, E, W_edge, b_dense, bias_edge, Wcomb_b, bias2, NPB, HB);
    scanA_kernel<<<NB, 256, 0, stream>>>(deg_i, pos, bsum, N);
    scanB_kernel<<<1, 256, 0, stream>>>(bsum, NB);
    scanC_kernel<<<NB, 256, 0, stream>>>(pos, cursor, bsum, N);
    scatter_kernel<<<(E + 255) / 256, 256, 0, stream>>>(dst, cursor, sorted_ed, E);
    efp_seg_kernel<<<(E + SEG_ROWS - 1) / SEG_ROWS, 256, 0, stream>>>(
        ef, sorted_ed, Wcomb_b, efp, nb_sum, E);
    ndp_lite_kernel<<<(int)(((size_t)N * 8 + 255) / 256), 256, 0, stream>>>(
        nb_sum, deg_i, nfp_b, ndp_b, N);
    final_kernel<<<(int)(((size_t)E * 4 + 255) / 256), 256, 0, stream>>>(
        efp, src, dst, ndp_b, nfp_b, bias2, ef_out, E);
}

// Round 14
// 358.424 us; speedup vs baseline: 1.2935x; 1.0585x over previous
//
#include <hip/hip_runtime.h>

#define D 64

typedef __attribute__((ext_vector_type(8))) short short8;
typedef __attribute__((ext_vector_type(4))) float f32x4;

__device__ __forceinline__ ushort f2b(float f) {
    union { float f; unsigned u; } x; x.f = f;
    unsigned r = x.u + 0x7FFFu + ((x.u >> 16) & 1u);   // RNE to bf16
    return (ushort)(r >> 16);
}
__device__ __forceinline__ float b2f(ushort u) {
    union { float f; unsigned u; } x; x.u = ((unsigned)u) << 16;
    return x.f;
}
__device__ __forceinline__ short8 pack8(float4 a, float4 b) {
    short8 r;
    r[0] = (short)f2b(a.x); r[1] = (short)f2b(a.y); r[2] = (short)f2b(a.z); r[3] = (short)f2b(a.w);
    r[4] = (short)f2b(b.x); r[5] = (short)f2b(b.y); r[6] = (short)f2b(b.z); r[7] = (short)f2b(b.w);
    return r;
}

#define LDA 72   // bf16 row stride for 64-wide LDS tiles (round-2 proven)

// ---------------------------------------------------------------------------
// fused_front: blocks [0, NPB)      -> node_proj + nfp via MFMA (64 rows/blk)
//              blocks [NPB,NPB+HB)  -> dst histogram
//              block  NPB+HB        -> Wcomb/bias2 setup
// Node path: A-frags streamed from global; Bn/Bd bf16 [n][k] LDS tables;
// GEMM1 -> relu -> f32 out + bf16 Vs bounce -> GEMM2 -> packed nfp store.
// ---------------------------------------------------------------------------
__global__ __launch_bounds__(256) void fused_front_kernel(
    const float* __restrict__ nf, const float* __restrict__ Wn,
    const float* __restrict__ bias, const float* __restrict__ Wd,   // full W_dense
    float* __restrict__ out, ushort* __restrict__ nfp_b, int N,
    const int* __restrict__ dst, int* __restrict__ deg_i, int E,
    const float* __restrict__ W_edge, const float* __restrict__ b_dense,
    const float* __restrict__ bias_edge, ushort* __restrict__ Wcomb_b,
    float* __restrict__ bias2, int NPB, int HB)
{
    __shared__ ushort Bn[64 * LDA];   // bf16 W_node  [n][k]   9216 B
    __shared__ ushort Bd[64 * LDA];   // bf16 0.5*Wd_bot [n][k] 9216 B
    __shared__ ushort Vs[64 * LDA];   // bf16 relu(nf@Wn+b)     9216 B
    const int tid = threadIdx.x;
    const int bid = blockIdx.x;

    if (bid < NPB) {
        const long row0 = (long)bid * 64;
        const int w = tid >> 6, lane = tid & 63;
        const int lr = lane & 15, g = lane >> 4;
        const bool odd = lane & 1;

        {   // stage both weight tables (transpose to [n][k], bf16)
            int k = tid >> 2, n0 = (tid & 3) * 16;
            const float4* wr = (const float4*)(Wn + (long)k * D + n0);
            float4 v0 = wr[0], v1 = wr[1], v2 = wr[2], v3 = wr[3];
            float vs[16] = {v0.x, v0.y, v0.z, v0.w, v1.x, v1.y, v1.z, v1.w,
                            v2.x, v2.y, v2.z, v2.w, v3.x, v3.y, v3.z, v3.w};
            #pragma unroll
            for (int j = 0; j < 16; ++j) Bn[(n0 + j) * LDA + k] = f2b(vs[j]);
            const float4* wd = (const float4*)(Wd + (long)(D + k) * D + n0);
            float4 u0 = wd[0], u1 = wd[1], u2 = wd[2], u3 = wd[3];
            float us[16] = {u0.x, u0.y, u0.z, u0.w, u1.x, u1.y, u1.z, u1.w,
                            u2.x, u2.y, u2.z, u2.w, u3.x, u3.y, u3.z, u3.w};
            #pragma unroll
            for (int j = 0; j < 16; ++j) Bd[(n0 + j) * LDA + k] = f2b(0.5f * us[j]);
        }

        // A-frags from global nf rows
        long era = row0 + 16 * w + lr; if (era >= N) era = N - 1;
        const float4* ap = (const float4*)(nf + era * D);
        float4 v0 = ap[2 * g], v1 = ap[2 * g + 1];
        float4 v2 = ap[8 + 2 * g], v3 = ap[8 + 2 * g + 1];
        short8 a0 = pack8(v0, v1), a1 = pack8(v2, v3);
        __syncthreads();

        // GEMM1: nf @ W_node
        f32x4 acc[4];
        #pragma unroll
        for (int t = 0; t < 4; ++t) {
            f32x4 z = {0.f, 0.f, 0.f, 0.f};
            short8 b0 = *(const short8*)&Bn[(16 * t + lr) * LDA + 8 * g];
            short8 b1 = *(const short8*)&Bn[(16 * t + lr) * LDA + 32 + 8 * g];
            z = __builtin_amdgcn_mfma_f32_16x16x32_bf16(a0, b0, z, 0, 0, 0);
            z = __builtin_amdgcn_mfma_f32_16x16x32_bf16(a1, b1, z, 0, 0, 0);
            acc[t] = z;
        }
        // epilogue1: relu+bias -> f32 out store + bf16 Vs bounce
        #pragma unroll
        for (int t = 0; t < 4; ++t) {
            int c = 16 * t + lr;
            float bb = bias[c];
            #pragma unroll
            for (int reg = 0; reg < 4; ++reg) {
                int r = 16 * w + 4 * g + reg;
                float v = fmaxf(acc[t][reg] + bb, 0.f);
                long rg = row0 + r;
                if (rg < N) out[rg * D + c] = v;
                Vs[r * LDA + c] = f2b(v);
            }
        }
        __syncthreads();

        // GEMM2: Vs @ (0.5*Wd_bot)
        short8 c0 = *(const short8*)&Vs[(16 * w + lr) * LDA + 8 * g];
        short8 c1 = *(const short8*)&Vs[(16 * w + lr) * LDA + 32 + 8 * g];
        f32x4 acc2[4];
        #pragma unroll
        for (int t = 0; t < 4; ++t) {
            f32x4 z = {0.f, 0.f, 0.f, 0.f};
            short8 b0 = *(const short8*)&Bd[(16 * t + lr) * LDA + 8 * g];
            short8 b1 = *(const short8*)&Bd[(16 * t + lr) * LDA + 32 + 8 * g];
            z = __builtin_amdgcn_mfma_f32_16x16x32_bf16(c0, b0, z, 0, 0, 0);
            z = __builtin_amdgcn_mfma_f32_16x16x32_bf16(c1, b1, z, 0, 0, 0);
            acc2[t] = z;
        }
        // packed bf16 nfp store (efp_stream pattern)
        const int rb = 16 * w + 4 * g + (odd ? 2 : 0);
        long e0 = row0 + rb, e1 = row0 + rb + 1;
        #pragma unroll
        for (int t = 0; t < 4; ++t) {
            float p0 = __shfl_xor(acc2[t][0], 1, 64);
            float p1 = __shfl_xor(acc2[t][1], 1, 64);
            float p2 = __shfl_xor(acc2[t][2], 1, 64);
            float p3 = __shfl_xor(acc2[t][3], 1, 64);
            float lo0, hi0, lo1, hi1;
            if (odd) { lo0 = p2; hi0 = acc2[t][2]; lo1 = p3; hi1 = acc2[t][3]; }
            else     { lo0 = acc2[t][0]; hi0 = p0; lo1 = acc2[t][1]; hi1 = p1; }
            int cbase = 16 * t + (lr & ~1);
            unsigned dw0 = ((unsigned)f2b(hi0) << 16) | (unsigned)f2b(lo0);
            unsigned dw1 = ((unsigned)f2b(hi1) << 16) | (unsigned)f2b(lo1);
            if (e0 < N) *(unsigned*)(nfp_b + e0 * D + cbase) = dw0;
            if (e1 < N) *(unsigned*)(nfp_b + e1 * D + cbase) = dw1;
        }
    } else if (bid < NPB + HB) {
        int i = (bid - NPB) * 256 + tid;
        if (i < E) atomicAdd(deg_i + dst[i], 1);
    } else {
        // setup: Wcomb_b[n*64+k] = bf16((W_edge @ Wd_top)[k][n]); bias2
        for (int idx = tid; idx < D * D; idx += 256) {
            int k = idx >> 6, n = idx & 63;
            float s = 0.f;
            #pragma unroll 8
            for (int j = 0; j < D; ++j)
                s = fmaf(W_edge[k * D + j], Wd[j * D + n], s);
            Wcomb_b[n * D + k] = f2b(s);
        }
        if (tid < D) bias2[tid] = b_dense[tid] + bias_edge[tid];
    }
}

// ---------------------------------------------------------------------------
// Counting sort of edges by dst: (hist in fused_front) -> scan x3 -> scatter
// ---------------------------------------------------------------------------
__global__ __launch_bounds__(256) void scanA_kernel(
    const int* __restrict__ deg_i, int* __restrict__ pos,
    int* __restrict__ bsum, int N)
{
    __shared__ int s[256];
    const int tid = threadIdx.x;
    const int i = blockIdx.x * 256 + tid;
    int v = (i < N) ? deg_i[i] : 0;
    s[tid] = v;
    __syncthreads();
    #pragma unroll
    for (int off = 1; off < 256; off <<= 1) {
        int t = (tid >= off) ? s[tid - off] : 0;
        __syncthreads();
        s[tid] += t;
        __syncthreads();
    }
    if (i < N) pos[i] = s[tid] - v;          // block-local exclusive
    if (tid == 255) bsum[blockIdx.x] = s[255];
}

__global__ __launch_bounds__(256) void scanB_kernel(int* __restrict__ bsum, int NB)
{
    __shared__ int s[256];
    const int tid = threadIdx.x;
    int v = (tid < NB) ? bsum[tid] : 0;
    s[tid] = v;
    __syncthreads();
    #pragma unroll
    for (int off = 1; off < 256; off <<= 1) {
        int t = (tid >= off) ? s[tid - off] : 0;
        __syncthreads();
        s[tid] += t;
        __syncthreads();
    }
    if (tid < NB) bsum[tid] = s[tid] - v;    // exclusive
}

__global__ __launch_bounds__(256) void scanC_kernel(
    const int* __restrict__ pos, int* __restrict__ cursor,
    const int* __restrict__ bsum, int N)
{
    int i = blockIdx.x * 256 + threadIdx.x;
    if (i < N) cursor[i] = pos[i] + bsum[blockIdx.x];
}

__global__ __launch_bounds__(256) void scatter_kernel(
    const int* __restrict__ dst, int* __restrict__ cursor,
    int2* __restrict__ sorted_ed, int E)
{
    int i = blockIdx.x * 256 + threadIdx.x;
    if (i < E) {
        int dv = dst[i];
        int slot = atomicAdd(cursor + dv, 1);
        sorted_ed[slot] = make_int2(i, dv);
    }
}

// ---------------------------------------------------------------------------
// efp_seg: 256 dst-sorted edges per block (4 MFMA tiles), 4 waves.
// (round-13 proven: 131 us; structure floor — left unchanged)
// ---------------------------------------------------------------------------
#define SEG_ROWS 256
#define SLSTR 34
__global__ __launch_bounds__(256) void efp_seg_kernel(
    const float* __restrict__ ef, const int2* __restrict__ sorted_ed,
    const ushort* __restrict__ Wt, ushort* __restrict__ efp,
    float* __restrict__ nb_sum, int E)
{
    __shared__ unsigned Slds[SEG_ROWS * SLSTR];   // 34816 B
    __shared__ int dsts[SEG_ROWS];                // 1024 B
    const int tid = threadIdx.x;
    const long s0 = (long)blockIdx.x * SEG_ROWS;

    const int w = tid >> 6, lane = tid & 63;
    const int lr = lane & 15, g = lane >> 4;
    const bool odd = lane & 1;

    long gde[4];
    #pragma unroll
    for (int tt = 0; tt < 4; ++tt) {
        long s = s0 + 64 * tt + 16 * w + lr;
        if (s >= E) s = E - 1;
        gde[tt] = (long)sorted_ed[s].x;
    }
    float4 va[4][4];
    #pragma unroll
    for (int tt = 0; tt < 4; ++tt) {
        const float4* ap = (const float4*)(ef + gde[tt] * D);
        va[tt][0] = ap[2 * g];     va[tt][1] = ap[2 * g + 1];
        va[tt][2] = ap[8 + 2 * g]; va[tt][3] = ap[8 + 2 * g + 1];
    }
    int rbl[4]; long seo[4][2];
    #pragma unroll
    for (int tt = 0; tt < 4; ++tt) {
        rbl[tt] = 64 * tt + 16 * w + 4 * g + (odd ? 2 : 0);
        long s = s0 + rbl[tt];
        if (s > E - 2) s = (E - 2) & ~1L;
        int4 q = *(const int4*)&sorted_ed[s];
        seo[tt][0] = (long)q.x * D;
        seo[tt][1] = (long)q.z * D;
    }
    {
        long s = s0 + tid;
        dsts[tid] = (s < E) ? sorted_ed[s].y : -1;
    }

    short8 bf0[4], bf1[4];
    #pragma unroll
    for (int t = 0; t < 4; ++t) {
        bf0[t] = *(const short8*)&Wt[(16 * t + lr) * D + 8 * g];
        bf1[t] = *(const short8*)&Wt[(16 * t + lr) * D + 32 + 8 * g];
    }

    #pragma unroll
    for (int tt = 0; tt < 4; ++tt) {
        short8 a0 = pack8(va[tt][0], va[tt][1]);
        short8 a1 = pack8(va[tt][2], va[tt][3]);
        f32x4 acc[4];
        #pragma unroll
        for (int t = 0; t < 4; ++t) {
            f32x4 z = {0.f, 0.f, 0.f, 0.f};
            z = __builtin_amdgcn_mfma_f32_16x16x32_bf16(a0, bf0[t], z, 0, 0, 0);
            z = __builtin_amdgcn_mfma_f32_16x16x32_bf16(a1, bf1[t], z, 0, 0, 0);
            acc[t] = z;
        }

        const int rb = rbl[tt];
        long sl0 = s0 + rb, sl1 = s0 + rb + 1;
        #pragma unroll
        for (int t = 0; t < 4; ++t) {
            float p0 = __shfl_xor(acc[t][0], 1, 64);
            float p1 = __shfl_xor(acc[t][1], 1, 64);
            float p2 = __shfl_xor(acc[t][2], 1, 64);
            float p3 = __shfl_xor(acc[t][3], 1, 64);
            float lo0, hi0, lo1, hi1;
            if (odd) { lo0 = p2; hi0 = acc[t][2]; lo1 = p3; hi1 = acc[t][3]; }
            else     { lo0 = acc[t][0]; hi0 = p0; lo1 = acc[t][1]; hi1 = p1; }
            int cbase = 16 * t + (lr & ~1);
            int dc = cbase >> 1;
            unsigned dw0 = ((unsigned)f2b(hi0) << 16) | (unsigned)f2b(lo0);
            unsigned dw1 = ((unsigned)f2b(hi1) << 16) | (unsigned)f2b(lo1);
            if (sl0 < E) *(unsigned*)(efp + seo[tt][0] + cbase) = dw0;
            if (sl1 < E) *(unsigned*)(efp + seo[tt][1] + cbase) = dw1;
            Slds[rb * SLSTR + dc]       = dw0;
            Slds[(rb + 1) * SLSTR + dc] = dw1;
        }
    }
    __syncthreads();

    {
        const int dwc = tid & 31;
        const int r0 = (tid >> 5) * 32;
        float seg0 = 0.f, seg1 = 0.f;
        int cur = dsts[r0];
        #pragma unroll 4
        for (int r = r0; r < r0 + 32; ++r) {
            int dv = dsts[r];
            unsigned u = Slds[r * SLSTR + dwc];
            if (dv != cur) {
                if (cur >= 0) {
                    atomicAdd(nb_sum + (long)cur * D + 2 * dwc, seg0);
                    atomicAdd(nb_sum + (long)cur * D + 2 * dwc + 1, seg1);
                }
                seg0 = seg1 = 0.f;
                cur = dv;
            }
            seg0 += b2f((ushort)(u & 0xffff));
            seg1 += b2f((ushort)(u >> 16));
        }
        if (cur >= 0) {
            atomicAdd(nb_sum + (long)cur * D + 2 * dwc, seg0);
            atomicAdd(nb_sum + (long)cur * D + 2 * dwc + 1, seg1);
        }
    }
}

// ---------------------------------------------------------------------------
// ndp_lite: ndp_b[n] = bf16( nb_sum[n]/max(deg,1) + nfp[n] ).  Elementwise.
// ---------------------------------------------------------------------------
__global__ __launch_bounds__(256) void ndp_lite_kernel(
    const float* __restrict__ nb_sum, const int* __restrict__ deg_i,
    const ushort* __restrict__ nfp_b, ushort* __restrict__ ndp_b, int N)
{
    long i = (long)blockIdx.x * 256 + threadIdx.x;   // group = (node, col-block)
    long node = i >> 3;
    int cb = (int)(i & 7);
    if (node >= N) return;
    float inv = 1.0f / fmaxf((float)deg_i[node], 1.0f);
    const float4* sp = (const float4*)(nb_sum + node * D + cb * 8);
    float4 x0 = sp[0], x1 = sp[1];
    short8 np = *(const short8*)(nfp_b + node * D + cb * 8);
    short8 r;
    r[0] = (short)f2b(x0.x * inv + b2f((ushort)np[0]));
    r[1] = (short)f2b(x0.y * inv + b2f((ushort)np[1]));
    r[2] = (short)f2b(x0.z * inv + b2f((ushort)np[2]));
    r[3] = (short)f2b(x0.w * inv + b2f((ushort)np[3]));
    r[4] = (short)f2b(x1.x * inv + b2f((ushort)np[4]));
    r[5] = (short)f2b(x1.y * inv + b2f((ushort)np[5]));
    r[6] = (short)f2b(x1.z * inv + b2f((ushort)np[6]));
    r[7] = (short)f2b(x1.w * inv + b2f((ushort)np[7]));
    *(short8*)(ndp_b + node * D + cb * 8) = r;
}

// ---------------------------------------------------------------------------
// final: ef_out = relu(efp + ndp[dst] + nfp[src] + bias2). Pure elementwise,
// plain float4 stores (NT stores measured -40us regression, round 11).
// ---------------------------------------------------------------------------
__global__ __launch_bounds__(256) void final_kernel(
    const ushort* __restrict__ efp, const int* __restrict__ src,
    const int* __restrict__ dst, const ushort* __restrict__ ndp_b,
    const ushort* __restrict__ nfp_b, const float* __restrict__ bias2,
    float* __restrict__ out, int E)
{
    long idx = (long)blockIdx.x * 256 + threadIdx.x;
    long e = idx >> 2;
    int q = (int)(idx & 3);
    if (e >= E) return;
    int dv = dst[e], sv = src[e];
    const short8* ep = (const short8*)(efp + e * D + q * 16);
    const short8* np = (const short8*)(ndp_b + (long)dv * D + q * 16);
    const short8* sp = (const short8*)(nfp_b + (long)sv * D + q * 16);
    short8 e0 = ep[0], e1 = ep[1];
    short8 n0 = np[0], n1 = np[1];
    short8 s0 = sp[0], s1 = sp[1];
    const float4* bp = (const float4*)(bias2 + q * 16);
    float4 b0 = bp[0], b1 = bp[1], b2 = bp[2], b3 = bp[3];

    float r[16];
    #pragma unroll
    for (int j = 0; j < 8; ++j) {
        r[j]     = b2f((ushort)e0[j]) + b2f((ushort)n0[j]) + b2f((ushort)s0[j]);
        r[8 + j] = b2f((ushort)e1[j]) + b2f((ushort)n1[j]) + b2f((ushort)s1[j]);
    }
    float4* op = (float4*)(out + e * D + q * 16);
    op[0] = make_float4(fmaxf(r[0] + b0.x, 0.f), fmaxf(r[1] + b0.y, 0.f),
                        fmaxf(r[2] + b0.z, 0.f), fmaxf(r[3] + b0.w, 0.f));
    op[1] = make_float4(fmaxf(r[4] + b1.x, 0.f), fmaxf(r[5] + b1.y, 0.f),
                        fmaxf(r[6] + b1.z, 0.f), fmaxf(r[7] + b1.w, 0.f));
    op[2] = make_float4(fmaxf(r[8] + b2.x, 0.f), fmaxf(r[9] + b2.y, 0.f),
                        fmaxf(r[10] + b2.z, 0.f), fmaxf(r[11] + b2.w, 0.f));
    op[3] = make_float4(fmaxf(r[12] + b3.x, 0.f), fmaxf(r[13] + b3.y, 0.f),
                        fmaxf(r[14] + b3.z, 0.f), fmaxf(r[15] + b3.w, 0.f));
}

// ---------------------------------------------------------------------------
extern "C" void kernel_launch(void* const* d_in, const int* in_sizes, int n_in,
                              void* d_out, int out_size, void* d_ws, size_t ws_size,
                              hipStream_t stream) {
    const float* nf        = (const float*)d_in[0];
    const float* ef        = (const float*)d_in[1];
    const int*   src       = (const int*)d_in[2];
    const int*   dst       = (const int*)d_in[3];
    const float* W_node    = (const float*)d_in[4];
    const float* W_edge    = (const float*)d_in[5];
    const float* bias_node = (const float*)d_in[6];
    const float* bias_edge = (const float*)d_in[7];
    const float* W_dense   = (const float*)d_in[8];
    const float* b_dense   = (const float*)d_in[9];

    const int N = in_sizes[0] / D;
    const int E = in_sizes[1] / D;
    const int NB = (N + 255) / 256;
    const int NPB = (N + 63) / 64;
    const int HB = (E + 255) / 256;

    float* nf_out = (float*)d_out;
    float* ef_out = (float*)d_out + (size_t)N * D;

    // ws layout: [zeroed: deg_i, nb_sum] then the rest
    char* p = (char*)d_ws;
    int*    deg_i    = (int*)p;     p += (size_t)N * 4;           // zeroed
    float*  nb_sum   = (float*)p;   p += (size_t)N * D * 4;       // zeroed, 12.8 MB
    size_t  zbytes   = (size_t)(p - (char*)d_ws);
    int*    pos      = (int*)p;     p += (size_t)N * 4;
    int*    cursor   = (int*)p;     p += (size_t)N * 4;
    int*    bsum     = (int*)p;     p += 256 * 4;
    int2*   sorted_ed= (int2*)p;    p += (size_t)E * 8;           // 6.4 MB
    ushort* nfp_b    = (ushort*)p;  p += (size_t)N * D * 2;
    ushort* ndp_b    = (ushort*)p;  p += (size_t)N * D * 2;
    ushort* Wcomb_b  = (ushort*)p;  p += D * D * 2;
    float*  bias2    = (float*)p;   p += 256;
    ushort* efp      = (ushort*)p;  /* E*D*2 = 102.4 MB */

    hipMemsetAsync(d_ws, 0, zbytes, stream);

    fused_front_kernel<<<NPB + HB + 1, 256, 0, stream>>>(
        nf, W_node, bias_node, W_dense, nf_out, nfp_b, N,
        dst, deg_i, E, W_edge, b_dense, bias_edge, Wcomb_b, bias2, NPB, HB);
    scanA_kernel<<<NB, 256, 0, stream>>>(deg_i, pos, bsum, N);
    scanB_kernel<<<1, 256, 0, stream>>>(bsum, NB);
    scanC_kernel<<<NB, 256, 0, stream>>>(pos, cursor, bsum, N);
    scatter_kernel<<<(E + 255) / 256, 256, 0, stream>>>(dst, cursor, sorted_ed, E);
    efp_seg_kernel<<<(E + SEG_ROWS - 1) / SEG_ROWS, 256, 0, stream>>>(
        ef, sorted_ed, Wcomb_b, efp, nb_sum, E);
    ndp_lite_kernel<<<(int)(((size_t)N * 8 + 255) / 256), 256, 0, stream>>>(
        nb_sum, deg_i, nfp_b, ndp_b, N);
    final_kernel<<<(int)(((size_t)E * 4 + 255) / 256), 256, 0, stream>>>(
        efp, src, dst, ndp_b, nfp_b, bias2, ef_out, E);
}

// Round 15
// 343.858 us; speedup vs baseline: 1.3483x; 1.0424x over previous
//
#include <hip/hip_runtime.h>

#define D 64

typedef __attribute__((ext_vector_type(8))) short short8;
typedef __attribute__((ext_vector_type(4))) float f32x4;

__device__ __forceinline__ ushort f2b(float f) {
    union { float f; unsigned u; } x; x.f = f;
    unsigned r = x.u + 0x7FFFu + ((x.u >> 16) & 1u);   // RNE to bf16
    return (ushort)(r >> 16);
}
__device__ __forceinline__ float b2f(ushort u) {
    union { float f; unsigned u; } x; x.u = ((unsigned)u) << 16;
    return x.f;
}
__device__ __forceinline__ short8 pack8(float4 a, float4 b) {
    short8 r;
    r[0] = (short)f2b(a.x); r[1] = (short)f2b(a.y); r[2] = (short)f2b(a.z); r[3] = (short)f2b(a.w);
    r[4] = (short)f2b(b.x); r[5] = (short)f2b(b.y); r[6] = (short)f2b(b.z); r[7] = (short)f2b(b.w);
    return r;
}

#define LDA 72   // bf16 row stride for 64-wide LDS tiles (round-2 proven)

// ---------------------------------------------------------------------------
// fused_front: blocks [0, NPB)      -> node_proj + nfp via MFMA (64 rows/blk)
//              blocks [NPB,NPB+HB)  -> dst histogram
//              block  NPB+HB        -> Wcomb/bias2 setup
// ---------------------------------------------------------------------------
__global__ __launch_bounds__(256) void fused_front_kernel(
    const float* __restrict__ nf, const float* __restrict__ Wn,
    const float* __restrict__ bias, const float* __restrict__ Wd,   // full W_dense
    float* __restrict__ out, ushort* __restrict__ nfp_b, int N,
    const int* __restrict__ dst, int* __restrict__ deg_i, int E,
    const float* __restrict__ W_edge, const float* __restrict__ b_dense,
    const float* __restrict__ bias_edge, ushort* __restrict__ Wcomb_b,
    float* __restrict__ bias2, int NPB, int HB)
{
    __shared__ ushort Bn[64 * LDA];   // bf16 W_node  [n][k]   9216 B
    __shared__ ushort Bd[64 * LDA];   // bf16 0.5*Wd_bot [n][k] 9216 B
    __shared__ ushort Vs[64 * LDA];   // bf16 relu(nf@Wn+b)     9216 B
    const int tid = threadIdx.x;
    const int bid = blockIdx.x;

    if (bid < NPB) {
        const long row0 = (long)bid * 64;
        const int w = tid >> 6, lane = tid & 63;
        const int lr = lane & 15, g = lane >> 4;
        const bool odd = lane & 1;

        {   // stage both weight tables (transpose to [n][k], bf16)
            int k = tid >> 2, n0 = (tid & 3) * 16;
            const float4* wr = (const float4*)(Wn + (long)k * D + n0);
            float4 v0 = wr[0], v1 = wr[1], v2 = wr[2], v3 = wr[3];
            float vs[16] = {v0.x, v0.y, v0.z, v0.w, v1.x, v1.y, v1.z, v1.w,
                            v2.x, v2.y, v2.z, v2.w, v3.x, v3.y, v3.z, v3.w};
            #pragma unroll
            for (int j = 0; j < 16; ++j) Bn[(n0 + j) * LDA + k] = f2b(vs[j]);
            const float4* wd = (const float4*)(Wd + (long)(D + k) * D + n0);
            float4 u0 = wd[0], u1 = wd[1], u2 = wd[2], u3 = wd[3];
            float us[16] = {u0.x, u0.y, u0.z, u0.w, u1.x, u1.y, u1.z, u1.w,
                            u2.x, u2.y, u2.z, u2.w, u3.x, u3.y, u3.z, u3.w};
            #pragma unroll
            for (int j = 0; j < 16; ++j) Bd[(n0 + j) * LDA + k] = f2b(0.5f * us[j]);
        }

        // A-frags from global nf rows
        long era = row0 + 16 * w + lr; if (era >= N) era = N - 1;
        const float4* ap = (const float4*)(nf + era * D);
        float4 v0 = ap[2 * g], v1 = ap[2 * g + 1];
        float4 v2 = ap[8 + 2 * g], v3 = ap[8 + 2 * g + 1];
        short8 a0 = pack8(v0, v1), a1 = pack8(v2, v3);
        __syncthreads();

        // GEMM1: nf @ W_node
        f32x4 acc[4];
        #pragma unroll
        for (int t = 0; t < 4; ++t) {
            f32x4 z = {0.f, 0.f, 0.f, 0.f};
            short8 b0 = *(const short8*)&Bn[(16 * t + lr) * LDA + 8 * g];
            short8 b1 = *(const short8*)&Bn[(16 * t + lr) * LDA + 32 + 8 * g];
            z = __builtin_amdgcn_mfma_f32_16x16x32_bf16(a0, b0, z, 0, 0, 0);
            z = __builtin_amdgcn_mfma_f32_16x16x32_bf16(a1, b1, z, 0, 0, 0);
            acc[t] = z;
        }
        // epilogue1: relu+bias -> f32 out store + bf16 Vs bounce
        #pragma unroll
        for (int t = 0; t < 4; ++t) {
            int c = 16 * t + lr;
            float bb = bias[c];
            #pragma unroll
            for (int reg = 0; reg < 4; ++reg) {
                int r = 16 * w + 4 * g + reg;
                float v = fmaxf(acc[t][reg] + bb, 0.f);
                long rg = row0 + r;
                if (rg < N) out[rg * D + c] = v;
                Vs[r * LDA + c] = f2b(v);
            }
        }
        __syncthreads();

        // GEMM2: Vs @ (0.5*Wd_bot)
        short8 c0 = *(const short8*)&Vs[(16 * w + lr) * LDA + 8 * g];
        short8 c1 = *(const short8*)&Vs[(16 * w + lr) * LDA + 32 + 8 * g];
        f32x4 acc2[4];
        #pragma unroll
        for (int t = 0; t < 4; ++t) {
            f32x4 z = {0.f, 0.f, 0.f, 0.f};
            short8 b0 = *(const short8*)&Bd[(16 * t + lr) * LDA + 8 * g];
            short8 b1 = *(const short8*)&Bd[(16 * t + lr) * LDA + 32 + 8 * g];
            z = __builtin_amdgcn_mfma_f32_16x16x32_bf16(c0, b0, z, 0, 0, 0);
            z = __builtin_amdgcn_mfma_f32_16x16x32_bf16(c1, b1, z, 0, 0, 0);
            acc2[t] = z;
        }
        // packed bf16 nfp store
        const int rb = 16 * w + 4 * g + (odd ? 2 : 0);
        long e0 = row0 + rb, e1 = row0 + rb + 1;
        #pragma unroll
        for (int t = 0; t < 4; ++t) {
            float p0 = __shfl_xor(acc2[t][0], 1, 64);
            float p1 = __shfl_xor(acc2[t][1], 1, 64);
            float p2 = __shfl_xor(acc2[t][2], 1, 64);
            float p3 = __shfl_xor(acc2[t][3], 1, 64);
            float lo0, hi0, lo1, hi1;
            if (odd) { lo0 = p2; hi0 = acc2[t][2]; lo1 = p3; hi1 = acc2[t][3]; }
            else     { lo0 = acc2[t][0]; hi0 = p0; lo1 = acc2[t][1]; hi1 = p1; }
            int cbase = 16 * t + (lr & ~1);
            unsigned dw0 = ((unsigned)f2b(hi0) << 16) | (unsigned)f2b(lo0);
            unsigned dw1 = ((unsigned)f2b(hi1) << 16) | (unsigned)f2b(lo1);
            if (e0 < N) *(unsigned*)(nfp_b + e0 * D + cbase) = dw0;
            if (e1 < N) *(unsigned*)(nfp_b + e1 * D + cbase) = dw1;
        }
    } else if (bid < NPB + HB) {
        int i = (bid - NPB) * 256 + tid;
        if (i < E) atomicAdd(deg_i + dst[i], 1);
    } else {
        // setup: Wcomb_b[n*64+k] = bf16((W_edge @ Wd_top)[k][n]); bias2
        for (int idx = tid; idx < D * D; idx += 256) {
            int k = idx >> 6, n = idx & 63;
            float s = 0.f;
            #pragma unroll 8
            for (int j = 0; j < D; ++j)
                s = fmaf(W_edge[k * D + j], Wd[j * D + n], s);
            Wcomb_b[n * D + k] = f2b(s);
        }
        if (tid < D) bias2[tid] = b_dense[tid] + bias_edge[tid];
    }
}

// ---------------------------------------------------------------------------
// Counting sort of edges by dst: (hist in fused_front) -> scan x3 -> scatter.
// sorted_eds[slot] = (eid, dst, src, 0)  — int4 so downstream never random-
// reads src[eid].
// ---------------------------------------------------------------------------
__global__ __launch_bounds__(256) void scanA_kernel(
    const int* __restrict__ deg_i, int* __restrict__ pos,
    int* __restrict__ bsum, int N)
{
    __shared__ int s[256];
    const int tid = threadIdx.x;
    const int i = blockIdx.x * 256 + tid;
    int v = (i < N) ? deg_i[i] : 0;
    s[tid] = v;
    __syncthreads();
    #pragma unroll
    for (int off = 1; off < 256; off <<= 1) {
        int t = (tid >= off) ? s[tid - off] : 0;
        __syncthreads();
        s[tid] += t;
        __syncthreads();
    }
    if (i < N) pos[i] = s[tid] - v;          // block-local exclusive
    if (tid == 255) bsum[blockIdx.x] = s[255];
}

__global__ __launch_bounds__(256) void scanB_kernel(int* __restrict__ bsum, int NB)
{
    __shared__ int s[256];
    const int tid = threadIdx.x;
    int v = (tid < NB) ? bsum[tid] : 0;
    s[tid] = v;
    __syncthreads();
    #pragma unroll
    for (int off = 1; off < 256; off <<= 1) {
        int t = (tid >= off) ? s[tid - off] : 0;
        __syncthreads();
        s[tid] += t;
        __syncthreads();
    }
    if (tid < NB) bsum[tid] = s[tid] - v;    // exclusive
}

__global__ __launch_bounds__(256) void scanC_kernel(
    const int* __restrict__ pos, int* __restrict__ cursor,
    const int* __restrict__ bsum, int N)
{
    int i = blockIdx.x * 256 + threadIdx.x;
    if (i < N) cursor[i] = pos[i] + bsum[blockIdx.x];
}

__global__ __launch_bounds__(256) void scatter_kernel(
    const int* __restrict__ dst, const int* __restrict__ src,
    int* __restrict__ cursor, int4* __restrict__ sorted_eds, int E)
{
    int i = blockIdx.x * 256 + threadIdx.x;
    if (i < E) {
        int dv = dst[i];
        int slot = atomicAdd(cursor + dv, 1);
        sorted_eds[slot] = make_int4(i, dv, src[i], 0);
    }
}

// ---------------------------------------------------------------------------
// efp_seg: 256 dst-sorted edges per block (4 MFMA tiles), 4 waves.
// ef-row gathers (the ONLY permutation here now) -> MFMA -> packed bf16
// dwords stored to efp in SLOT ORDER (sequential) AND a bf16 LDS tile
// (stride 34 -> 2-way-free banks); one barrier; parallel segment walk
// (32-row strip x dword-col) -> f32 atomics into nb_sum.
// ---------------------------------------------------------------------------
#define SEG_ROWS 256
#define SLSTR 34
__global__ __launch_bounds__(256) void efp_seg_kernel(
    const float* __restrict__ ef, const int4* __restrict__ sorted_eds,
    const ushort* __restrict__ Wt, ushort* __restrict__ efp,
    float* __restrict__ nb_sum, int E)
{
    __shared__ unsigned Slds[SEG_ROWS * SLSTR];   // 34816 B
    __shared__ int dsts[SEG_ROWS];                // 1024 B
    const int tid = threadIdx.x;
    const long s0 = (long)blockIdx.x * SEG_ROWS;

    const int w = tid >> 6, lane = tid & 63;
    const int lr = lane & 15, g = lane >> 4;
    const bool odd = lane & 1;

    // gather-row eids (per-lane, no LDS dependency)
    long gde[4];
    #pragma unroll
    for (int tt = 0; tt < 4; ++tt) {
        long s = s0 + 64 * tt + 16 * w + lr;
        if (s >= E) s = E - 1;
        gde[tt] = (long)sorted_eds[s].x;
    }
    // issue ALL ef gathers (16 dwordx4 per lane outstanding)
    float4 va[4][4];
    #pragma unroll
    for (int tt = 0; tt < 4; ++tt) {
        const float4* ap = (const float4*)(ef + gde[tt] * D);
        va[tt][0] = ap[2 * g];     va[tt][1] = ap[2 * g + 1];
        va[tt][2] = ap[8 + 2 * g]; va[tt][3] = ap[8 + 2 * g + 1];
    }
    // dsts for the walk (one per thread)
    {
        long s = s0 + tid;
        dsts[tid] = (s < E) ? sorted_eds[s].y : -1;
    }

    // B fragments (L1-resident)
    short8 bf0[4], bf1[4];
    #pragma unroll
    for (int t = 0; t < 4; ++t) {
        bf0[t] = *(const short8*)&Wt[(16 * t + lr) * D + 8 * g];
        bf1[t] = *(const short8*)&Wt[(16 * t + lr) * D + 32 + 8 * g];
    }

    #pragma unroll
    for (int tt = 0; tt < 4; ++tt) {
        short8 a0 = pack8(va[tt][0], va[tt][1]);
        short8 a1 = pack8(va[tt][2], va[tt][3]);
        f32x4 acc[4];
        #pragma unroll
        for (int t = 0; t < 4; ++t) {
            f32x4 z = {0.f, 0.f, 0.f, 0.f};
            z = __builtin_amdgcn_mfma_f32_16x16x32_bf16(a0, bf0[t], z, 0, 0, 0);
            z = __builtin_amdgcn_mfma_f32_16x16x32_bf16(a1, bf1[t], z, 0, 0, 0);
            acc[t] = z;
        }

        // packed stores: SEQUENTIAL slot-order efp + LDS tile
        const int rb = 64 * tt + 16 * w + 4 * g + (odd ? 2 : 0);
        long sl0 = s0 + rb, sl1 = s0 + rb + 1;
        #pragma unroll
        for (int t = 0; t < 4; ++t) {
            float p0 = __shfl_xor(acc[t][0], 1, 64);
            float p1 = __shfl_xor(acc[t][1], 1, 64);
            float p2 = __shfl_xor(acc[t][2], 1, 64);
            float p3 = __shfl_xor(acc[t][3], 1, 64);
            float lo0, hi0, lo1, hi1;
            if (odd) { lo0 = p2; hi0 = acc[t][2]; lo1 = p3; hi1 = acc[t][3]; }
            else     { lo0 = acc[t][0]; hi0 = p0; lo1 = acc[t][1]; hi1 = p1; }
            int cbase = 16 * t + (lr & ~1);
            int dc = cbase >> 1;
            unsigned dw0 = ((unsigned)f2b(hi0) << 16) | (unsigned)f2b(lo0);
            unsigned dw1 = ((unsigned)f2b(hi1) << 16) | (unsigned)f2b(lo1);
            if (sl0 < E) *(unsigned*)(efp + sl0 * D + cbase) = dw0;
            if (sl1 < E) *(unsigned*)(efp + sl1 * D + cbase) = dw1;
            Slds[rb * SLSTR + dc]       = dw0;
            Slds[(rb + 1) * SLSTR + dc] = dw1;
        }
    }
    __syncthreads();

    // parallel segment walk: dword-col = tid&31 (2 f32 cols), strip of 32 rows.
    {
        const int dwc = tid & 31;
        const int r0 = (tid >> 5) * 32;
        float seg0 = 0.f, seg1 = 0.f;
        int cur = dsts[r0];
        #pragma unroll 4
        for (int r = r0; r < r0 + 32; ++r) {
            int dv = dsts[r];
            unsigned u = Slds[r * SLSTR + dwc];
            if (dv != cur) {
                if (cur >= 0) {
                    atomicAdd(nb_sum + (long)cur * D + 2 * dwc, seg0);
                    atomicAdd(nb_sum + (long)cur * D + 2 * dwc + 1, seg1);
                }
                seg0 = seg1 = 0.f;
                cur = dv;
            }
            seg0 += b2f((ushort)(u & 0xffff));
            seg1 += b2f((ushort)(u >> 16));
        }
        if (cur >= 0) {
            atomicAdd(nb_sum + (long)cur * D + 2 * dwc, seg0);
            atomicAdd(nb_sum + (long)cur * D + 2 * dwc + 1, seg1);
        }
    }
}

// ---------------------------------------------------------------------------
// ndp_lite: ndp_b[n] = bf16( nb_sum[n]/max(deg,1) + nfp[n] ).  Elementwise.
// ---------------------------------------------------------------------------
__global__ __launch_bounds__(256) void ndp_lite_kernel(
    const float* __restrict__ nb_sum, const int* __restrict__ deg_i,
    const ushort* __restrict__ nfp_b, ushort* __restrict__ ndp_b, int N)
{
    long i = (long)blockIdx.x * 256 + threadIdx.x;   // group = (node, col-block)
    long node = i >> 3;
    int cb = (int)(i & 7);
    if (node >= N) return;
    float inv = 1.0f / fmaxf((float)deg_i[node], 1.0f);
    const float4* sp = (const float4*)(nb_sum + node * D + cb * 8);
    float4 x0 = sp[0], x1 = sp[1];
    short8 np = *(const short8*)(nfp_b + node * D + cb * 8);
    short8 r;
    r[0] = (short)f2b(x0.x * inv + b2f((ushort)np[0]));
    r[1] = (short)f2b(x0.y * inv + b2f((ushort)np[1]));
    r[2] = (short)f2b(x0.z * inv + b2f((ushort)np[2]));
    r[3] = (short)f2b(x0.w * inv + b2f((ushort)np[3]));
    r[4] = (short)f2b(x1.x * inv + b2f((ushort)np[4]));
    r[5] = (short)f2b(x1.y * inv + b2f((ushort)np[5]));
    r[6] = (short)f2b(x1.z * inv + b2f((ushort)np[6]));
    r[7] = (short)f2b(x1.w * inv + b2f((ushort)np[7]));
    *(short8*)(ndp_b + node * D + cb * 8) = r;
}

// ---------------------------------------------------------------------------
// final (slot order): for slot s, (eid,dv,sv) = sorted_eds[s];
// out[eid] = relu(efp[s] + ndp[dv] + nfp[sv] + bias2).
// efp read sequential; ndp gathers monotone (dst-sorted, L1-reused);
// nfp gather random; out write scattered in contiguous 256B/edge chunks.
// ---------------------------------------------------------------------------
__global__ __launch_bounds__(256) void final_kernel(
    const ushort* __restrict__ efp, const int4* __restrict__ sorted_eds,
    const ushort* __restrict__ ndp_b, const ushort* __restrict__ nfp_b,
    const float* __restrict__ bias2, float* __restrict__ out, int E)
{
    long idx = (long)blockIdx.x * 256 + threadIdx.x;
    long s = idx >> 2;
    int q = (int)(idx & 3);
    if (s >= E) return;
    int4 ed = sorted_eds[s];
    long eid = ed.x;
    int dv = ed.y, sv = ed.z;
    const short8* ep = (const short8*)(efp + s * D + q * 16);
    const short8* np = (const short8*)(ndp_b + (long)dv * D + q * 16);
    const short8* sp = (const short8*)(nfp_b + (long)sv * D + q * 16);
    short8 e0 = ep[0], e1 = ep[1];
    short8 n0 = np[0], n1 = np[1];
    short8 s0 = sp[0], s1 = sp[1];
    const float4* bp = (const float4*)(bias2 + q * 16);
    float4 b0 = bp[0], b1 = bp[1], b2 = bp[2], b3 = bp[3];

    float r[16];
    #pragma unroll
    for (int j = 0; j < 8; ++j) {
        r[j]     = b2f((ushort)e0[j]) + b2f((ushort)n0[j]) + b2f((ushort)s0[j]);
        r[8 + j] = b2f((ushort)e1[j]) + b2f((ushort)n1[j]) + b2f((ushort)s1[j]);
    }
    float4* op = (float4*)(out + eid * D + q * 16);
    op[0] = make_float4(fmaxf(r[0] + b0.x, 0.f), fmaxf(r[1] + b0.y, 0.f),
                        fmaxf(r[2] + b0.z, 0.f), fmaxf(r[3] + b0.w, 0.f));
    op[1] = make_float4(fmaxf(r[4] + b1.x, 0.f), fmaxf(r[5] + b1.y, 0.f),
                        fmaxf(r[6] + b1.z, 0.f), fmaxf(r[7] + b1.w, 0.f));
    op[2] = make_float4(fmaxf(r[8] + b2.x, 0.f), fmaxf(r[9] + b2.y, 0.f),
                        fmaxf(r[10] + b2.z, 0.f), fmaxf(r[11] + b2.w, 0.f));
    op[3] = make_float4(fmaxf(r[12] + b3.x, 0.f), fmaxf(r[13] + b3.y, 0.f),
                        fmaxf(r[14] + b3.z, 0.f), fmaxf(r[15] + b3.w, 0.f));
}

// ---------------------------------------------------------------------------
extern "C" void kernel_launch(void* const* d_in, const int* in_sizes, int n_in,
                              void* d_out, int out_size, void* d_ws, size_t ws_size,
                              hipStream_t stream) {
    const float* nf        = (const float*)d_in[0];
    const float* ef        = (const float*)d_in[1];
    const int*   src       = (const int*)d_in[2];
    const int*   dst       = (const int*)d_in[3];
    const float* W_node    = (const float*)d_in[4];
    const float* W_edge    = (const float*)d_in[5];
    const float* bias_node = (const float*)d_in[6];
    const float* bias_edge = (const float*)d_in[7];
    const float* W_dense   = (const float*)d_in[8];
    const float* b_dense   = (const float*)d_in[9];

    const int N = in_sizes[0] / D;
    const int E = in_sizes[1] / D;
    const int NB = (N + 255) / 256;
    const int NPB = (N + 63) / 64;
    const int HB = (E + 255) / 256;

    float* nf_out = (float*)d_out;
    float* ef_out = (float*)d_out + (size_t)N * D;

    // ws layout: [zeroed: deg_i, nb_sum] then the rest
    char* p = (char*)d_ws;
    int*    deg_i    = (int*)p;     p += (size_t)N * 4;           // zeroed
    float*  nb_sum   = (float*)p;   p += (size_t)N * D * 4;       // zeroed, 12.8 MB
    size_t  zbytes   = (size_t)(p - (char*)d_ws);
    int*    pos      = (int*)p;     p += (size_t)N * 4;
    int*    cursor   = (int*)p;     p += (size_t)N * 4;
    int*    bsum     = (int*)p;     p += 256 * 4;
    int4*   sorted_eds=(int4*)p;    p += (size_t)E * 16;          // 12.8 MB
    ushort* nfp_b    = (ushort*)p;  p += (size_t)N * D * 2;
    ushort* ndp_b    = (ushort*)p;  p += (size_t)N * D * 2;
    ushort* Wcomb_b  = (ushort*)p;  p += D * D * 2;
    float*  bias2    = (float*)p;   p += 256;
    ushort* efp      = (ushort*)p;  /* E*D*2 = 102.4 MB, slot order */

    hipMemsetAsync(d_ws, 0, zbytes, stream);

    fused_front_kernel<<<NPB + HB + 1, 256, 0, stream>>>(
        nf, W_node, bias_node, W_dense, nf_out, nfp_b, N,
        dst, deg_i, E, W_edge, b_dense, bias_edge, Wcomb_b, bias2, NPB, HB);
    scanA_kernel<<<NB, 256, 0, stream>>>(deg_i, pos, bsum, N);
    scanB_kernel<<<1, 256, 0, stream>>>(bsum, NB);
    scanC_kernel<<<NB, 256, 0, stream>>>(pos, cursor, bsum, N);
    scatter_kernel<<<(E + 255) / 256, 256, 0, stream>>>(dst, src, cursor, sorted_eds, E);
    efp_seg_kernel<<<(E + SEG_ROWS - 1) / SEG_ROWS, 256, 0, stream>>>(
        ef, sorted_eds, Wcomb_b, efp, nb_sum, E);
    ndp_lite_kernel<<<(int)(((size_t)N * 8 + 255) / 256), 256, 0, stream>>>(
        nb_sum, deg_i, nfp_b, ndp_b, N);
    final_kernel<<<(int)(((size_t)E * 4 + 255) / 256), 256, 0, stream>>>(
        efp, sorted_eds, ndp_b, nfp_b, bias2, ef_out, E);
}

// Round 16
// 326.366 us; speedup vs baseline: 1.4206x; 1.0536x over previous
//
#include <hip/hip_runtime.h>

#define D 64

typedef __attribute__((ext_vector_type(8))) short short8;
typedef __attribute__((ext_vector_type(4))) float f32x4;

__device__ __forceinline__ ushort f2b(float f) {
    union { float f; unsigned u; } x; x.f = f;
    unsigned r = x.u + 0x7FFFu + ((x.u >> 16) & 1u);   // RNE to bf16
    return (ushort)(r >> 16);
}
__device__ __forceinline__ float b2f(ushort u) {
    union { float f; unsigned u; } x; x.u = ((unsigned)u) << 16;
    return x.f;
}
__device__ __forceinline__ short8 pack8(float4 a, float4 b) {
    short8 r;
    r[0] = (short)f2b(a.x); r[1] = (short)f2b(a.y); r[2] = (short)f2b(a.z); r[3] = (short)f2b(a.w);
    r[4] = (short)f2b(b.x); r[5] = (short)f2b(b.y); r[6] = (short)f2b(b.z); r[7] = (short)f2b(b.w);
    return r;
}

#define LDA 72   // bf16 row stride for 64-wide LDS tiles (round-2 proven)

// ---------------------------------------------------------------------------
// fused_front: blocks [0, NPB)      -> node_proj + nfp via MFMA (64 rows/blk)
//              blocks [NPB,NPB+HB)  -> dst histogram
//              block  NPB+HB        -> Wcomb/bias2 setup
// ---------------------------------------------------------------------------
__global__ __launch_bounds__(256) void fused_front_kernel(
    const float* __restrict__ nf, const float* __restrict__ Wn,
    const float* __restrict__ bias, const float* __restrict__ Wd,   // full W_dense
    float* __restrict__ out, ushort* __restrict__ nfp_b, int N,
    const int* __restrict__ dst, int* __restrict__ deg_i, int E,
    const float* __restrict__ W_edge, const float* __restrict__ b_dense,
    const float* __restrict__ bias_edge, ushort* __restrict__ Wcomb_b,
    float* __restrict__ bias2, int NPB, int HB)
{
    __shared__ ushort Bn[64 * LDA];   // bf16 W_node  [n][k]   9216 B
    __shared__ ushort Bd[64 * LDA];   // bf16 0.5*Wd_bot [n][k] 9216 B
    __shared__ ushort Vs[64 * LDA];   // bf16 relu(nf@Wn+b)     9216 B
    const int tid = threadIdx.x;
    const int bid = blockIdx.x;

    if (bid < NPB) {
        const long row0 = (long)bid * 64;
        const int w = tid >> 6, lane = tid & 63;
        const int lr = lane & 15, g = lane >> 4;
        const bool odd = lane & 1;

        {   // stage both weight tables (transpose to [n][k], bf16)
            int k = tid >> 2, n0 = (tid & 3) * 16;
            const float4* wr = (const float4*)(Wn + (long)k * D + n0);
            float4 v0 = wr[0], v1 = wr[1], v2 = wr[2], v3 = wr[3];
            float vs[16] = {v0.x, v0.y, v0.z, v0.w, v1.x, v1.y, v1.z, v1.w,
                            v2.x, v2.y, v2.z, v2.w, v3.x, v3.y, v3.z, v3.w};
            #pragma unroll
            for (int j = 0; j < 16; ++j) Bn[(n0 + j) * LDA + k] = f2b(vs[j]);
            const float4* wd = (const float4*)(Wd + (long)(D + k) * D + n0);
            float4 u0 = wd[0], u1 = wd[1], u2 = wd[2], u3 = wd[3];
            float us[16] = {u0.x, u0.y, u0.z, u0.w, u1.x, u1.y, u1.z, u1.w,
                            u2.x, u2.y, u2.z, u2.w, u3.x, u3.y, u3.z, u3.w};
            #pragma unroll
            for (int j = 0; j < 16; ++j) Bd[(n0 + j) * LDA + k] = f2b(0.5f * us[j]);
        }

        // A-frags from global nf rows
        long era = row0 + 16 * w + lr; if (era >= N) era = N - 1;
        const float4* ap = (const float4*)(nf + era * D);
        float4 v0 = ap[2 * g], v1 = ap[2 * g + 1];
        float4 v2 = ap[8 + 2 * g], v3 = ap[8 + 2 * g + 1];
        short8 a0 = pack8(v0, v1), a1 = pack8(v2, v3);
        __syncthreads();

        // GEMM1: nf @ W_node
        f32x4 acc[4];
        #pragma unroll
        for (int t = 0; t < 4; ++t) {
            f32x4 z = {0.f, 0.f, 0.f, 0.f};
            short8 b0 = *(const short8*)&Bn[(16 * t + lr) * LDA + 8 * g];
            short8 b1 = *(const short8*)&Bn[(16 * t + lr) * LDA + 32 + 8 * g];
            z = __builtin_amdgcn_mfma_f32_16x16x32_bf16(a0, b0, z, 0, 0, 0);
            z = __builtin_amdgcn_mfma_f32_16x16x32_bf16(a1, b1, z, 0, 0, 0);
            acc[t] = z;
        }
        // epilogue1: relu+bias -> f32 out store + bf16 Vs bounce
        #pragma unroll
        for (int t = 0; t < 4; ++t) {
            int c = 16 * t + lr;
            float bb = bias[c];
            #pragma unroll
            for (int reg = 0; reg < 4; ++reg) {
                int r = 16 * w + 4 * g + reg;
                float v = fmaxf(acc[t][reg] + bb, 0.f);
                long rg = row0 + r;
                if (rg < N) out[rg * D + c] = v;
                Vs[r * LDA + c] = f2b(v);
            }
        }
        __syncthreads();

        // GEMM2: Vs @ (0.5*Wd_bot)
        short8 c0 = *(const short8*)&Vs[(16 * w + lr) * LDA + 8 * g];
        short8 c1 = *(const short8*)&Vs[(16 * w + lr) * LDA + 32 + 8 * g];
        f32x4 acc2[4];
        #pragma unroll
        for (int t = 0; t < 4; ++t) {
            f32x4 z = {0.f, 0.f, 0.f, 0.f};
            short8 b0 = *(const short8*)&Bd[(16 * t + lr) * LDA + 8 * g];
            short8 b1 = *(const short8*)&Bd[(16 * t + lr) * LDA + 32 + 8 * g];
            z = __builtin_amdgcn_mfma_f32_16x16x32_bf16(c0, b0, z, 0, 0, 0);
            z = __builtin_amdgcn_mfma_f32_16x16x32_bf16(c1, b1, z, 0, 0, 0);
            acc2[t] = z;
        }
        // packed bf16 nfp store
        const int rb = 16 * w + 4 * g + (odd ? 2 : 0);
        long e0 = row0 + rb, e1 = row0 + rb + 1;
        #pragma unroll
        for (int t = 0; t < 4; ++t) {
            float p0 = __shfl_xor(acc2[t][0], 1, 64);
            float p1 = __shfl_xor(acc2[t][1], 1, 64);
            float p2 = __shfl_xor(acc2[t][2], 1, 64);
            float p3 = __shfl_xor(acc2[t][3], 1, 64);
            float lo0, hi0, lo1, hi1;
            if (odd) { lo0 = p2; hi0 = acc2[t][2]; lo1 = p3; hi1 = acc2[t][3]; }
            else     { lo0 = acc2[t][0]; hi0 = p0; lo1 = acc2[t][1]; hi1 = p1; }
            int cbase = 16 * t + (lr & ~1);
            unsigned dw0 = ((unsigned)f2b(hi0) << 16) | (unsigned)f2b(lo0);
            unsigned dw1 = ((unsigned)f2b(hi1) << 16) | (unsigned)f2b(lo1);
            if (e0 < N) *(unsigned*)(nfp_b + e0 * D + cbase) = dw0;
            if (e1 < N) *(unsigned*)(nfp_b + e1 * D + cbase) = dw1;
        }
    } else if (bid < NPB + HB) {
        int i = (bid - NPB) * 256 + tid;
        if (i < E) atomicAdd(deg_i + dst[i], 1);
    } else {
        // setup: Wcomb_b[n*64+k] = bf16((W_edge @ Wd_top)[k][n]); bias2
        for (int idx = tid; idx < D * D; idx += 256) {
            int k = idx >> 6, n = idx & 63;
            float s = 0.f;
            #pragma unroll 8
            for (int j = 0; j < D; ++j)
                s = fmaf(W_edge[k * D + j], Wd[j * D + n], s);
            Wcomb_b[n * D + k] = f2b(s);
        }
        if (tid < D) bias2[tid] = b_dense[tid] + bias_edge[tid];
    }
}

// ---------------------------------------------------------------------------
// Counting sort by dst: (hist in fused_front) -> scanA/scanB -> scatter.
// scanC is folded into scatter: slot = pos[dv] + bsum[dv>>8] + cnt[dv]++.
// sorted_eds[slot] = (eid, dst, src, 0).
// ---------------------------------------------------------------------------
__global__ __launch_bounds__(256) void scanA_kernel(
    const int* __restrict__ deg_i, int* __restrict__ pos,
    int* __restrict__ bsum, int N)
{
    __shared__ int s[256];
    const int tid = threadIdx.x;
    const int i = blockIdx.x * 256 + tid;
    int v = (i < N) ? deg_i[i] : 0;
    s[tid] = v;
    __syncthreads();
    #pragma unroll
    for (int off = 1; off < 256; off <<= 1) {
        int t = (tid >= off) ? s[tid - off] : 0;
        __syncthreads();
        s[tid] += t;
        __syncthreads();
    }
    if (i < N) pos[i] = s[tid] - v;          // block-local exclusive
    if (tid == 255) bsum[blockIdx.x] = s[255];
}

__global__ __launch_bounds__(256) void scanB_kernel(int* __restrict__ bsum, int NB)
{
    __shared__ int s[256];
    const int tid = threadIdx.x;
    int v = (tid < NB) ? bsum[tid] : 0;
    s[tid] = v;
    __syncthreads();
    #pragma unroll
    for (int off = 1; off < 256; off <<= 1) {
        int t = (tid >= off) ? s[tid - off] : 0;
        __syncthreads();
        s[tid] += t;
        __syncthreads();
    }
    if (tid < NB) bsum[tid] = s[tid] - v;    // exclusive
}

__global__ __launch_bounds__(256) void scatter_kernel(
    const int* __restrict__ dst, const int* __restrict__ src,
    const int* __restrict__ pos, const int* __restrict__ bsum,
    int* __restrict__ cnt, int4* __restrict__ sorted_eds, int E)
{
    int i = blockIdx.x * 256 + threadIdx.x;
    if (i < E) {
        int dv = dst[i];
        int slot = pos[dv] + bsum[dv >> 8] + atomicAdd(cnt + dv, 1);
        sorted_eds[slot] = make_int4(i, dv, src[i], 0);
    }
}

// ---------------------------------------------------------------------------
// efp_seg: 256 dst-sorted edges per block (4 MFMA tiles), 4 waves.
// ef-row gathers (the only permutation) -> MFMA -> packed bf16 dwords
// stored to efp in SLOT ORDER (sequential) AND bf16 LDS tile (stride 34);
// one barrier; parallel segment walk -> f32 atomics into nb_sum.
// ---------------------------------------------------------------------------
#define SEG_ROWS 256
#define SLSTR 34
__global__ __launch_bounds__(256) void efp_seg_kernel(
    const float* __restrict__ ef, const int4* __restrict__ sorted_eds,
    const ushort* __restrict__ Wt, ushort* __restrict__ efp,
    float* __restrict__ nb_sum, int E)
{
    __shared__ unsigned Slds[SEG_ROWS * SLSTR];   // 34816 B
    __shared__ int dsts[SEG_ROWS];                // 1024 B
    const int tid = threadIdx.x;
    const long s0 = (long)blockIdx.x * SEG_ROWS;

    const int w = tid >> 6, lane = tid & 63;
    const int lr = lane & 15, g = lane >> 4;
    const bool odd = lane & 1;

    long gde[4];
    #pragma unroll
    for (int tt = 0; tt < 4; ++tt) {
        long s = s0 + 64 * tt + 16 * w + lr;
        if (s >= E) s = E - 1;
        gde[tt] = (long)sorted_eds[s].x;
    }
    float4 va[4][4];
    #pragma unroll
    for (int tt = 0; tt < 4; ++tt) {
        const float4* ap = (const float4*)(ef + gde[tt] * D);
        va[tt][0] = ap[2 * g];     va[tt][1] = ap[2 * g + 1];
        va[tt][2] = ap[8 + 2 * g]; va[tt][3] = ap[8 + 2 * g + 1];
    }
    {
        long s = s0 + tid;
        dsts[tid] = (s < E) ? sorted_eds[s].y : -1;
    }

    short8 bf0[4], bf1[4];
    #pragma unroll
    for (int t = 0; t < 4; ++t) {
        bf0[t] = *(const short8*)&Wt[(16 * t + lr) * D + 8 * g];
        bf1[t] = *(const short8*)&Wt[(16 * t + lr) * D + 32 + 8 * g];
    }

    #pragma unroll
    for (int tt = 0; tt < 4; ++tt) {
        short8 a0 = pack8(va[tt][0], va[tt][1]);
        short8 a1 = pack8(va[tt][2], va[tt][3]);
        f32x4 acc[4];
        #pragma unroll
        for (int t = 0; t < 4; ++t) {
            f32x4 z = {0.f, 0.f, 0.f, 0.f};
            z = __builtin_amdgcn_mfma_f32_16x16x32_bf16(a0, bf0[t], z, 0, 0, 0);
            z = __builtin_amdgcn_mfma_f32_16x16x32_bf16(a1, bf1[t], z, 0, 0, 0);
            acc[t] = z;
        }

        const int rb = 64 * tt + 16 * w + 4 * g + (odd ? 2 : 0);
        long sl0 = s0 + rb, sl1 = s0 + rb + 1;
        #pragma unroll
        for (int t = 0; t < 4; ++t) {
            float p0 = __shfl_xor(acc[t][0], 1, 64);
            float p1 = __shfl_xor(acc[t][1], 1, 64);
            float p2 = __shfl_xor(acc[t][2], 1, 64);
            float p3 = __shfl_xor(acc[t][3], 1, 64);
            float lo0, hi0, lo1, hi1;
            if (odd) { lo0 = p2; hi0 = acc[t][2]; lo1 = p3; hi1 = acc[t][3]; }
            else     { lo0 = acc[t][0]; hi0 = p0; lo1 = acc[t][1]; hi1 = p1; }
            int cbase = 16 * t + (lr & ~1);
            int dc = cbase >> 1;
            unsigned dw0 = ((unsigned)f2b(hi0) << 16) | (unsigned)f2b(lo0);
            unsigned dw1 = ((unsigned)f2b(hi1) << 16) | (unsigned)f2b(lo1);
            if (sl0 < E) *(unsigned*)(efp + sl0 * D + cbase) = dw0;
            if (sl1 < E) *(unsigned*)(efp + sl1 * D + cbase) = dw1;
            Slds[rb * SLSTR + dc]       = dw0;
            Slds[(rb + 1) * SLSTR + dc] = dw1;
        }
    }
    __syncthreads();

    {
        const int dwc = tid & 31;
        const int r0 = (tid >> 5) * 32;
        float seg0 = 0.f, seg1 = 0.f;
        int cur = dsts[r0];
        #pragma unroll 4
        for (int r = r0; r < r0 + 32; ++r) {
            int dv = dsts[r];
            unsigned u = Slds[r * SLSTR + dwc];
            if (dv != cur) {
                if (cur >= 0) {
                    atomicAdd(nb_sum + (long)cur * D + 2 * dwc, seg0);
                    atomicAdd(nb_sum + (long)cur * D + 2 * dwc + 1, seg1);
                }
                seg0 = seg1 = 0.f;
                cur = dv;
            }
            seg0 += b2f((ushort)(u & 0xffff));
            seg1 += b2f((ushort)(u >> 16));
        }
        if (cur >= 0) {
            atomicAdd(nb_sum + (long)cur * D + 2 * dwc, seg0);
            atomicAdd(nb_sum + (long)cur * D + 2 * dwc + 1, seg1);
        }
    }
}

// ---------------------------------------------------------------------------
// final (slot order, ndp fused): for slot s, (eid,dv,sv) = sorted_eds[s];
// out[eid] = relu(efp[s] + nb_sum[dv]/max(deg,1) + nfp[dv] + nfp[sv] + bias2).
// efp read sequential (L3-hot); nb_sum/deg/nfp[dv] reads monotone (L1-reused
// across each dst run); nfp[sv] is the only random gather.
// ---------------------------------------------------------------------------
__global__ __launch_bounds__(256) void final_kernel(
    const ushort* __restrict__ efp, const int4* __restrict__ sorted_eds,
    const float* __restrict__ nb_sum, const int* __restrict__ deg_i,
    const ushort* __restrict__ nfp_b, const float* __restrict__ bias2,
    float* __restrict__ out, int E)
{
    long idx = (long)blockIdx.x * 256 + threadIdx.x;
    long s = idx >> 2;
    int q = (int)(idx & 3);
    if (s >= E) return;
    int4 ed = sorted_eds[s];
    long eid = ed.x;
    int dv = ed.y, sv = ed.z;

    const short8* ep = (const short8*)(efp + s * D + q * 16);
    const float4* nb = (const float4*)(nb_sum + (long)dv * D + q * 16);
    const short8* nd = (const short8*)(nfp_b + (long)dv * D + q * 16);
    const short8* sp = (const short8*)(nfp_b + (long)sv * D + q * 16);
    short8 e0 = ep[0], e1 = ep[1];
    float4 x0 = nb[0], x1 = nb[1], x2 = nb[2], x3 = nb[3];
    short8 d0 = nd[0], d1 = nd[1];
    short8 s0 = sp[0], s1 = sp[1];
    float inv = 1.0f / fmaxf((float)deg_i[dv], 1.0f);
    const float4* bp = (const float4*)(bias2 + q * 16);
    float4 b0 = bp[0], b1 = bp[1], b2 = bp[2], b3 = bp[3];

    float xb[16] = {x0.x, x0.y, x0.z, x0.w, x1.x, x1.y, x1.z, x1.w,
                    x2.x, x2.y, x2.z, x2.w, x3.x, x3.y, x3.z, x3.w};
    float r[16];
    #pragma unroll
    for (int j = 0; j < 8; ++j) {
        r[j]     = b2f((ushort)e0[j]) + xb[j] * inv + b2f((ushort)d0[j]) + b2f((ushort)s0[j]);
        r[8 + j] = b2f((ushort)e1[j]) + xb[8 + j] * inv + b2f((ushort)d1[j]) + b2f((ushort)s1[j]);
    }
    float4* op = (float4*)(out + eid * D + q * 16);
    op[0] = make_float4(fmaxf(r[0] + b0.x, 0.f), fmaxf(r[1] + b0.y, 0.f),
                        fmaxf(r[2] + b0.z, 0.f), fmaxf(r[3] + b0.w, 0.f));
    op[1] = make_float4(fmaxf(r[4] + b1.x, 0.f), fmaxf(r[5] + b1.y, 0.f),
                        fmaxf(r[6] + b1.z, 0.f), fmaxf(r[7] + b1.w, 0.f));
    op[2] = make_float4(fmaxf(r[8] + b2.x, 0.f), fmaxf(r[9] + b2.y, 0.f),
                        fmaxf(r[10] + b2.z, 0.f), fmaxf(r[11] + b2.w, 0.f));
    op[3] = make_float4(fmaxf(r[12] + b3.x, 0.f), fmaxf(r[13] + b3.y, 0.f),
                        fmaxf(r[14] + b3.z, 0.f), fmaxf(r[15] + b3.w, 0.f));
}

// ---------------------------------------------------------------------------
extern "C" void kernel_launch(void* const* d_in, const int* in_sizes, int n_in,
                              void* d_out, int out_size, void* d_ws, size_t ws_size,
                              hipStream_t stream) {
    const float* nf        = (const float*)d_in[0];
    const float* ef        = (const float*)d_in[1];
    const int*   src       = (const int*)d_in[2];
    const int*   dst       = (const int*)d_in[3];
    const float* W_node    = (const float*)d_in[4];
    const float* W_edge    = (const float*)d_in[5];
    const float* bias_node = (const float*)d_in[6];
    const float* bias_edge = (const float*)d_in[7];
    const float* W_dense   = (const float*)d_in[8];
    const float* b_dense   = (const float*)d_in[9];

    const int N = in_sizes[0] / D;
    const int E = in_sizes[1] / D;
    const int NB = (N + 255) / 256;
    const int NPB = (N + 63) / 64;
    const int HB = (E + 255) / 256;

    float* nf_out = (float*)d_out;
    float* ef_out = (float*)d_out + (size_t)N * D;

    // ws layout: [zeroed: deg_i, nb_sum, cnt] then the rest
    char* p = (char*)d_ws;
    int*    deg_i    = (int*)p;     p += (size_t)N * 4;           // zeroed
    float*  nb_sum   = (float*)p;   p += (size_t)N * D * 4;       // zeroed, 12.8 MB
    int*    cnt      = (int*)p;     p += (size_t)N * 4;           // zeroed
    size_t  zbytes   = (size_t)(p - (char*)d_ws);
    int*    pos      = (int*)p;     p += (size_t)N * 4;
    int*    bsum     = (int*)p;     p += 256 * 4;
    int4*   sorted_eds=(int4*)p;    p += (size_t)E * 16;          // 12.8 MB
    ushort* nfp_b    = (ushort*)p;  p += (size_t)N * D * 2;
    ushort* Wcomb_b  = (ushort*)p;  p += D * D * 2;
    float*  bias2    = (float*)p;   p += 256;
    ushort* efp      = (ushort*)p;  /* E*D*2 = 102.4 MB, slot order */

    hipMemsetAsync(d_ws, 0, zbytes, stream);

    fused_front_kernel<<<NPB + HB + 1, 256, 0, stream>>>(
        nf, W_node, bias_node, W_dense, nf_out, nfp_b, N,
        dst, deg_i, E, W_edge, b_dense, bias_edge, Wcomb_b, bias2, NPB, HB);
    scanA_kernel<<<NB, 256, 0, stream>>>(deg_i, pos, bsum, N);
    scanB_kernel<<<1, 256, 0, stream>>>(bsum, NB);
    scatter_kernel<<<(E + 255) / 256, 256, 0, stream>>>(dst, src, pos, bsum, cnt,
                                                        sorted_eds, E);
    efp_seg_kernel<<<(E + SEG_ROWS - 1) / SEG_ROWS, 256, 0, stream>>>(
        ef, sorted_eds, Wcomb_b, efp, nb_sum, E);
    final_kernel<<<(int)(((size_t)E * 4 + 255) / 256), 256, 0, stream>>>(
        efp, sorted_eds, nb_sum, deg_i, nfp_b, bias2, ef_out, E);
}